// Round 6
// baseline (104.620 us; speedup 1.0000x reference)
//
#include <hip/hip_runtime.h>

#define S_TOT 37448
#define OUT_T 5704
#define EMB 256

typedef unsigned short u16;
typedef __bf16 bf16x8 __attribute__((ext_vector_type(8)));
typedef float f32x4 __attribute__((ext_vector_type(4)));
typedef unsigned short u16x4 __attribute__((ext_vector_type(4)));
typedef unsigned short u16x8 __attribute__((ext_vector_type(8)));

__device__ __forceinline__ u16 f2bf(float f) {
  union { float f; unsigned int i; } v;
  v.f = f;
  unsigned int x = v.i;
  return (u16)((x + 0x7fffu + ((x >> 16) & 1u)) >> 16);
}
__device__ __forceinline__ float bfl(unsigned u) {
  union { unsigned u; float f; } t; t.u = u << 16; return t.f;
}
__device__ __forceinline__ float bfh(unsigned u) {
  union { unsigned u; float f; } t; t.u = u & 0xffff0000u; return t.f;
}

#define GLOAD_LDS16(g, l)                                                     \
  __builtin_amdgcn_global_load_lds((const __attribute__((address_space(1))) void*)(g), \
                                   (__attribute__((address_space(3))) void*)(l), 16, 0, 0)

// ---------------- layers 0-2: embedding gather (f32 exact, float4/thread) ---
__global__ __launch_bounds__(256) void emb_small(
    const int* __restrict__ value, const int* __restrict__ depth,
    const int* __restrict__ position,
    const float* __restrict__ ve0, const float* __restrict__ pe0, const float* __restrict__ de0,
    const float* __restrict__ ve1, const float* __restrict__ pe1, const float* __restrict__ de1,
    const float* __restrict__ ve2, const float* __restrict__ pe2, const float* __restrict__ de2,
    float* __restrict__ out) {
  const int tok = blockIdx.x * 4 + (threadIdx.x >> 6);  // 4 tokens per block
  const int lane = threadIdx.x & 63;
  const int b = tok / 584;
  const int t = tok - b * 584;
  const float *ve, *pe, *de;
  if (t < 8)       { ve = ve0; pe = pe0; de = de0; }
  else if (t < 72) { ve = ve1; pe = pe1; de = de1; }
  else             { ve = ve2; pe = pe2; de = de2; }
  const long base = (long)b * S_TOT + t;
  const int v = value[base];
  const int d = depth[base];
  const int p0 = position[base * 3 + 0];
  const int p1 = position[base * 3 + 1];
  const int p2 = position[base * 3 + 2];
  const int e = lane * 4;
  const float4 x = *(const float4*)(ve + v * EMB + e);
  const float4 y = *(const float4*)(pe + p0 * EMB + e);
  const float4 z = *(const float4*)(pe + (64 + p1) * EMB + e);
  const float4 u = *(const float4*)(pe + (128 + p2) * EMB + e);
  const float4 w = *(const float4*)(de + d * EMB + e);
  float4 r;
  r.x = x.x + y.x + z.x + u.x + w.x;
  r.y = x.y + y.y + z.y + u.y + w.y;
  r.z = x.z + y.z + z.z + u.z + w.z;
  r.w = x.w + y.w + z.w + u.w + w.w;
  *(float4*)(out + ((long)b * OUT_T + t) * EMB + e) = r;
}

// ------- Projected tables: P_kk = W_kk @ [ve; pe0; pe1; pe2] ----------------
// Rows 0..3 = ve, 4..67 = pe0, 68..131 = pe1, 132..195 = pe2 (196.. garbage).
// Reads RAW f32 W(O,E,k) (strided) — no transpose pass needed.
__global__ __launch_bounds__(512) void proj_tables(
    const float* __restrict__ ve3, const float* __restrict__ pe3, const float* __restrict__ w3,
    const float* __restrict__ ve4, const float* __restrict__ pe4, const float* __restrict__ w4,
    u16* __restrict__ T3, u16* __restrict__ T4) {
  __shared__ __align__(16) u16 As[64 * 32];
  __shared__ __align__(16) u16 Bs[256 * 32];
  const int bid = blockIdx.x;  // 0..47
  const int p = bid >> 2, rb = bid & 3;
  const float *ve, *pe, *wr_;
  u16* To;
  int CK, kk;
  if (p < 4) { ve = ve3; pe = pe3; wr_ = w3; CK = 4; kk = p;     To = T3 + kk * 65536; }
  else       { ve = ve4; pe = pe4; wr_ = w4; CK = 8; kk = p - 4; To = T4 + kk * 65536; }
  const int tid = threadIdx.x;
  const int lane = tid & 63, wid = tid >> 6;
  const int wr = wid >> 2, wc = wid & 3;
  const int fr = lane & 15, fq = lane >> 4;
  const int row0 = rb * 64;

  // A staging: 8 threads/row, 4 cols each, XOR granule swizzle
  const int arow = tid >> 3, acg = tid & 7;
  const int agran = acg >> 1, ahalf = acg & 1;
  const int aoff = arow * 32 + (agran ^ ((arow >> 1) & 3)) * 8 + ahalf * 4;
  const int gr = row0 + arow;
  const int per = (gr - 4) < 191 ? (gr - 4) : 191;
  const float* asrc = (gr < 4) ? (ve + gr * 256) : (pe + per * 256);

  // B staging: thread covers rows rl (j=0,1), content granule sl = lane&3
  const int brl = wid * 16 + (lane >> 2);
  const int bsl = lane & 3;

  f32x4 acc[2][4];
#pragma unroll
  for (int m = 0; m < 2; ++m)
#pragma unroll
    for (int n = 0; n < 4; ++n) acc[m][n] = (f32x4){0.f, 0.f, 0.f, 0.f};

  for (int s = 0; s < 8; ++s) {
    {  // stage A (f32 table row -> bf16)
      const float4 x = *(const float4*)(asrc + s * 32 + acg * 4);
      u16x4 pk;
      pk[0] = f2bf(x.x); pk[1] = f2bf(x.y); pk[2] = f2bf(x.z); pk[3] = f2bf(x.w);
      *(u16x4*)(&As[aoff]) = pk;
    }
#pragma unroll
    for (int j = 0; j < 2; ++j) {  // stage B from raw W, strided f32
      const int rl = j * 128 + brl;
      const int slot = bsl ^ ((rl >> 1) & 3);
      const float* src = wr_ + (long)rl * (256 * CK) + (s * 32 + bsl * 8) * CK + kk;
      u16x8 r;
#pragma unroll
      for (int c = 0; c < 8; ++c) r[c] = f2bf(src[c * CK]);
      *(u16x8*)(&Bs[rl * 32 + slot * 8]) = r;
    }
    __syncthreads();
    bf16x8 af[2], bfv[4];
#pragma unroll
    for (int m = 0; m < 2; ++m) {
      const int r = wr * 32 + m * 16 + fr;
      u16x8 t = *(const u16x8*)(&As[r * 32 + (fq ^ ((r >> 1) & 3)) * 8]);
      af[m] = __builtin_bit_cast(bf16x8, t);
    }
#pragma unroll
    for (int n = 0; n < 4; ++n) {
      const int o = wc * 64 + n * 16 + fr;
      u16x8 t = *(const u16x8*)(&Bs[o * 32 + (fq ^ ((o >> 1) & 3)) * 8]);
      bfv[n] = __builtin_bit_cast(bf16x8, t);
    }
#pragma unroll
    for (int m = 0; m < 2; ++m)
#pragma unroll
      for (int n = 0; n < 4; ++n)
        acc[m][n] = __builtin_amdgcn_mfma_f32_16x16x32_bf16(af[m], bfv[n], acc[m][n], 0, 0, 0);
    __syncthreads();
  }
#pragma unroll
  for (int m = 0; m < 2; ++m)
#pragma unroll
    for (int reg = 0; reg < 4; ++reg) {
      const int r = row0 + wr * 32 + m * 16 + fq * 4 + reg;
#pragma unroll
      for (int n = 0; n < 4; ++n)
        To[r * 256 + wc * 64 + n * 16 + fr] = f2bf(acc[m][n][reg]);
    }
}

// ------- main conv: pure gather-add over projected tables -------------------
// 512 threads: thread owns 4 cols (one uint2 = 4 bf16 per term), 8 rows.
template <int CK, int LOG2T, int S0, int OUT0>
__device__ __forceinline__ void gather_tile(
    int bid, const int* __restrict__ value, const int* __restrict__ position,
    const u16* __restrict__ Tp, const float* __restrict__ bias,
    float* __restrict__ out, unsigned* idxs) {
  constexpr int T = 1 << LOG2T;
  const int tid = threadIdx.x;
  const int row0 = bid * 64;
  for (int e = tid; e < 64 * CK; e += 512) {
    const int r = e / CK, kk = e % CK;
    const int grow = row0 + r;
    const int b = grow >> LOG2T, to = grow & (T - 1);
    const long sidx = (long)b * S_TOT + (S0 + to * CK + kk);
    const int* pp = position + sidx * 3;
    idxs[e] = (unsigned)value[sidx] | ((unsigned)pp[0] << 8) |
              ((unsigned)pp[1] << 16) | ((unsigned)pp[2] << 24);
  }
  __syncthreads();
  const int c = tid & 63;
  const int o0 = c * 4;          // 4 output cols
  const int rg = tid >> 6;       // 0..7 row-group of 8 rows
  const float4 bz = *(const float4*)(bias + o0);
#pragma unroll 2
  for (int r0 = 0; r0 < 8; ++r0) {
    const int r = rg * 8 + r0;
    float s0 = bz.x, s1 = bz.y, s2 = bz.z, s3 = bz.w;
#pragma unroll
    for (int kk = 0; kk < CK; ++kk) {
      const unsigned q = idxs[r * CK + kk];
      const u16* tb = Tp + kk * 65536;
      const uint2 a0 = *(const uint2*)(tb + (q & 255u) * 256 + o0);
      const uint2 a1 = *(const uint2*)(tb + (4 + ((q >> 8) & 255u)) * 256 + o0);
      const uint2 a2 = *(const uint2*)(tb + (68 + ((q >> 16) & 255u)) * 256 + o0);
      const uint2 a3 = *(const uint2*)(tb + (132 + (q >> 24)) * 256 + o0);
      s0 += bfl(a0.x); s1 += bfh(a0.x); s2 += bfl(a0.y); s3 += bfh(a0.y);
      s0 += bfl(a1.x); s1 += bfh(a1.x); s2 += bfl(a1.y); s3 += bfh(a1.y);
      s0 += bfl(a2.x); s1 += bfh(a2.x); s2 += bfl(a2.y); s3 += bfh(a2.y);
      s0 += bfl(a3.x); s1 += bfh(a3.x); s2 += bfl(a3.y); s3 += bfh(a3.y);
    }
    const int grow = row0 + r;
    const int b = grow >> LOG2T, to = grow & (T - 1);
    *(float4*)(out + (long)(b * OUT_T + OUT0 + to) * 256 + o0) =
        make_float4(s0, s1, s2, s3);
  }
}

__global__ __launch_bounds__(512) void conv_gather(
    const int* __restrict__ value, const int* __restrict__ position,
    const u16* __restrict__ T3, const float* __restrict__ b3,
    const u16* __restrict__ T4, const float* __restrict__ b4,
    float* __restrict__ out) {
  __shared__ unsigned idxs[64 * 8];
  const int g = blockIdx.x / 5, r = blockIdx.x % 5;
  if (r == 0)
    gather_tile<4, 10, 584, 584>(g, value, position, T3, b3, out, idxs);
  else
    gather_tile<8, 12, 4680, 1608>(g * 4 + (r - 1), value, position, T4, b4,
                                   out, idxs);
}

// ================= FALLBACK (ws too small; raw-W staging path) ==============
template <int K, int LOG2T, int CK, int S0, int OUT0>
__device__ __forceinline__ void conv_tile(
    int bid, const int* __restrict__ value, const int* __restrict__ position,
    const float* __restrict__ ve, const float* __restrict__ pe,
    const float* __restrict__ wraw, const float* __restrict__ bias,
    float* __restrict__ out,
    u16 (*As)[64 * 32], u16 (*Bs)[256 * 32], unsigned* idxc) {
  constexpr int T = 1 << LOG2T;
  constexpr int NS = K / 32;
  const int tid = threadIdx.x;
  const int lane = tid & 63;
  const int wid = tid >> 6;
  const int wr = wid >> 2;
  const int wc = wid & 3;
  const int fr = lane & 15;
  const int fq = lane >> 4;
  const int row0 = bid * 64;
  for (int e = tid; e < 64 * CK; e += 512) {
    const int r = e / CK, kk = e % CK;
    const int grow = row0 + r;
    const int b = grow >> LOG2T;
    const int to = grow & (T - 1);
    const long sidx = (long)b * S_TOT + (S0 + to * CK + kk);
    const int* pp = position + sidx * 3;
    idxc[e] = (unsigned)value[sidx] | ((unsigned)pp[0] << 8) |
              ((unsigned)pp[1] << 16) | ((unsigned)pp[2] << 24);
  }
  __syncthreads();
  const int arow = tid >> 3;
  const int acg = tid & 7;
  const int agran = acg >> 1, ahalf = acg & 1;
  const int aoff = arow * 32 + (agran ^ ((arow >> 1) & 3)) * 8 + ahalf * 4;
  auto gatherA = [&](int s, float4& r) {
    const int kk = s >> 3;
    const int e0 = (s & 7) * 32 + acg * 4;
    const unsigned q = idxc[arow * CK + kk];
    const int v = q & 255, p0 = (q >> 8) & 255, p1 = (q >> 16) & 255, p2 = q >> 24;
    float4 x = *(const float4*)(ve + v * EMB + e0);
    float4 y = *(const float4*)(pe + p0 * EMB + e0);
    float4 z = *(const float4*)(pe + (64 + p1) * EMB + e0);
    float4 u = *(const float4*)(pe + (128 + p2) * EMB + e0);
    r.x = x.x + y.x + z.x + u.x;
    r.y = x.y + y.y + z.y + u.y;
    r.z = x.z + y.z + z.z + u.z;
    r.w = x.w + y.w + z.w + u.w;
  };
  auto writeA = [&](int buf, const float4& r) {
    u16x4 p;
    p[0] = f2bf(r.x); p[1] = f2bf(r.y); p[2] = f2bf(r.z); p[3] = f2bf(r.w);
    *(u16x4*)(&As[buf][aoff]) = p;
  };
  auto issueB = [&](int s, int buf) {
    const int o = tid >> 1;
    const int hr = tid & 1;
    const int kk = s >> 3, e0 = (s & 7) * 32;
    const int osw = (o >> 1) & 3;
#pragma unroll
    for (int g2 = 0; g2 < 2; ++g2) {
      const int g = hr * 2 + g2;
      u16x8 r;
#pragma unroll
      for (int c = 0; c < 8; ++c)
        r[c] = f2bf(wraw[(long)o * (EMB * CK) + (e0 + g * 8 + c) * CK + kk]);
      *(u16x8*)(&Bs[buf][o * 32 + (g ^ osw) * 8]) = r;
    }
  };
  f32x4 acc[2][4];
#pragma unroll
  for (int m = 0; m < 2; ++m)
#pragma unroll
    for (int n = 0; n < 4; ++n) acc[m][n] = (f32x4){0.f, 0.f, 0.f, 0.f};
  {
    float4 a0;
    gatherA(0, a0);
    issueB(0, 0);
    writeA(0, a0);
  }
  __syncthreads();
  int cur = 0;
  for (int s = 0; s < NS; ++s) {
    const int nxt = cur ^ 1;
    const bool more = (s + 1 < NS);
    float4 pa;
    if (more) {
      gatherA(s + 1, pa);
      issueB(s + 1, nxt);
    }
    bf16x8 af[2], bfv[4];
#pragma unroll
    for (int m = 0; m < 2; ++m) {
      const int r = wr * 32 + m * 16 + fr;
      u16x8 t = *(const u16x8*)(&As[cur][r * 32 + (fq ^ ((r >> 1) & 3)) * 8]);
      af[m] = __builtin_bit_cast(bf16x8, t);
    }
#pragma unroll
    for (int n = 0; n < 4; ++n) {
      const int o = wc * 64 + n * 16 + fr;
      u16x8 t = *(const u16x8*)(&Bs[cur][o * 32 + (fq ^ ((o >> 1) & 3)) * 8]);
      bfv[n] = __builtin_bit_cast(bf16x8, t);
    }
#pragma unroll
    for (int m = 0; m < 2; ++m)
#pragma unroll
      for (int n = 0; n < 4; ++n)
        acc[m][n] = __builtin_amdgcn_mfma_f32_16x16x32_bf16(af[m], bfv[n], acc[m][n], 0, 0, 0);
    if (more) writeA(nxt, pa);
    __syncthreads();
    cur = nxt;
  }
  float bz[4];
#pragma unroll
  for (int n = 0; n < 4; ++n) bz[n] = bias[wc * 64 + n * 16 + fr];
#pragma unroll
  for (int m = 0; m < 2; ++m) {
#pragma unroll
    for (int reg = 0; reg < 4; ++reg) {
      const int grow = row0 + wr * 32 + m * 16 + fq * 4 + reg;
      const int bb = grow >> LOG2T;
      const int to = grow & (T - 1);
      float* op = out + ((long)bb * OUT_T + OUT0 + to) * EMB + wc * 64 + fr;
#pragma unroll
      for (int n = 0; n < 4; ++n) op[n * 16] = acc[m][n][reg] + bz[n];
    }
  }
}

__global__ __launch_bounds__(512, 4) void conv_fused(
    const int* __restrict__ value, const int* __restrict__ position,
    const float* __restrict__ ve3, const float* __restrict__ pe3,
    const float* __restrict__ w3, const float* __restrict__ b3,
    const float* __restrict__ ve4, const float* __restrict__ pe4,
    const float* __restrict__ w4, const float* __restrict__ b4,
    float* __restrict__ out) {
  __shared__ __align__(16) u16 As[2][64 * 32];
  __shared__ __align__(16) u16 Bs[2][256 * 32];
  __shared__ __align__(16) unsigned idxc[64 * 8];
  const int g = blockIdx.x / 5, r = blockIdx.x % 5;
  if (r == 0)
    conv_tile<1024, 10, 4, 584, 584>(g, value, position, ve3, pe3, w3, b3,
                                     out, As, Bs, idxc);
  else
    conv_tile<2048, 12, 8, 4680, 1608>(g * 4 + (r - 1), value, position, ve4,
                                       pe4, w4, b4, out, As, Bs, idxc);
}

extern "C" void kernel_launch(void* const* d_in, const int* in_sizes, int n_in,
                              void* d_out, int out_size, void* d_ws, size_t ws_size,
                              hipStream_t stream) {
  const int* value = (const int*)d_in[0];
  const int* depth = (const int*)d_in[1];
  const int* position = (const int*)d_in[2];
  const float* ve0 = (const float*)d_in[3];
  const float* pe0 = (const float*)d_in[4];
  const float* ve1 = (const float*)d_in[5];
  const float* pe1 = (const float*)d_in[6];
  const float* ve2 = (const float*)d_in[7];
  const float* pe2 = (const float*)d_in[8];
  const float* ve3 = (const float*)d_in[9];
  const float* pe3 = (const float*)d_in[10];
  const float* ve4 = (const float*)d_in[11];
  const float* pe4 = (const float*)d_in[12];
  const float* de0 = (const float*)d_in[13];
  const float* de1 = (const float*)d_in[14];
  const float* de2 = (const float*)d_in[15];
  const float* w3 = (const float*)d_in[16];
  const float* b3 = (const float*)d_in[17];
  const float* w4 = (const float*)d_in[18];
  const float* b4 = (const float*)d_in[19];
  float* out = (float*)d_out;

  u16* T3 = (u16*)d_ws;
  u16* T4 = T3 + 4 * 65536;
  const size_t need = (size_t)(12 * 65536) * sizeof(u16);

  emb_small<<<1168, 256, 0, stream>>>(value, depth, position, ve0, pe0, de0,
                                      ve1, pe1, de1, ve2, pe2, de2, out);
  if (ws_size >= need) {
    proj_tables<<<48, 512, 0, stream>>>(ve3, pe3, w3, ve4, pe4, w4, T3, T4);
    conv_gather<<<640, 512, 0, stream>>>(value, position, T3, b3, T4, b4, out);
  } else {
    conv_fused<<<640, 512, 0, stream>>>(value, position, ve3, pe3, w3, b3,
                                        ve4, pe4, w4, b4, out);
  }
}

// Round 7
// 66.838 us; speedup vs baseline: 1.5653x; 1.5653x over previous
//
#include <hip/hip_runtime.h>

#define S_TOT 37448
#define OUT_T 5704
#define EMB 256

typedef unsigned short u16;
typedef __bf16 bf16x8 __attribute__((ext_vector_type(8)));
typedef float f32x4 __attribute__((ext_vector_type(4)));
typedef unsigned short u16x4 __attribute__((ext_vector_type(4)));
typedef unsigned short u16x8 __attribute__((ext_vector_type(8)));

__device__ __forceinline__ u16 f2bf(float f) {
  union { float f; unsigned int i; } v;
  v.f = f;
  unsigned int x = v.i;
  return (u16)((x + 0x7fffu + ((x >> 16) & 1u)) >> 16);
}
__device__ __forceinline__ float bfl(unsigned u) {
  union { unsigned u; float f; } t; t.u = u << 16; return t.f;
}
__device__ __forceinline__ float bfh(unsigned u) {
  union { unsigned u; float f; } t; t.u = u & 0xffff0000u; return t.f;
}

#define GLOAD_LDS16(g, l)                                                     \
  __builtin_amdgcn_global_load_lds((const __attribute__((address_space(1))) void*)(g), \
                                   (__attribute__((address_space(3))) void*)(l), 16, 0, 0)

// ------- W repack: f32 (O,E,k) -> bf16 Wt[o][kk*256+e]  (coalesced) ---------
__global__ __launch_bounds__(256) void transpose_w(
    const float* __restrict__ w3, const float* __restrict__ w4,
    u16* __restrict__ wt3, u16* __restrict__ wt4) {
  const int i = blockIdx.x * 256 + threadIdx.x;
  if (i < 256 * 1024) {
    const int o = i >> 10, c = i & 1023, kk = c >> 8, e = c & 255;
    wt3[i] = f2bf(w3[o * 1024 + e * 4 + kk]);
  }
  if (i < 256 * 2048) {
    const int o = i >> 11, c = i & 2047, kk = c >> 8, e = c & 255;
    wt4[i] = f2bf(w4[o * 2048 + e * 8 + kk]);
  }
}

// ------- Projected tables: P_kk = W_kk @ [ve; pe0; pe1; pe2] ----------------
// Rows 0..3 = ve, 4..67 = pe0, 68..131 = pe1, 132..195 = pe2 (196.. garbage).
__global__ __launch_bounds__(512) void proj_tables(
    const float* __restrict__ ve3, const float* __restrict__ pe3, const u16* __restrict__ wt3,
    const float* __restrict__ ve4, const float* __restrict__ pe4, const u16* __restrict__ wt4,
    u16* __restrict__ T3, u16* __restrict__ T4) {
  __shared__ __align__(16) u16 As[64 * 32];
  __shared__ __align__(16) u16 Bs[256 * 32];
  const int bid = blockIdx.x;  // 0..47
  const int p = bid >> 2, rb = bid & 3;
  const float *ve, *pe;
  const u16* wt;
  u16* To;
  int K, kk;
  if (p < 4) { ve = ve3; pe = pe3; wt = wt3; K = 1024; kk = p;     To = T3 + kk * 65536; }
  else       { ve = ve4; pe = pe4; wt = wt4; K = 2048; kk = p - 4; To = T4 + kk * 65536; }
  const int tid = threadIdx.x;
  const int lane = tid & 63, wid = tid >> 6;
  const int wr = wid >> 2, wc = wid & 3;
  const int fr = lane & 15, fq = lane >> 4;
  const int row0 = rb * 64;

  const int arow = tid >> 3, acg = tid & 7;
  const int agran = acg >> 1, ahalf = acg & 1;
  const int aoff = arow * 32 + (agran ^ ((arow >> 1) & 3)) * 8 + ahalf * 4;
  const int gr = row0 + arow;
  const int per = (gr - 4) < 191 ? (gr - 4) : 191;
  const float* asrc = (gr < 4) ? (ve + gr * 256) : (pe + per * 256);

  f32x4 acc[2][4];
#pragma unroll
  for (int m = 0; m < 2; ++m)
#pragma unroll
    for (int n = 0; n < 4; ++n) acc[m][n] = (f32x4){0.f, 0.f, 0.f, 0.f};

  for (int s = 0; s < 8; ++s) {
    {  // stage A (f32 table row -> bf16)
      const float4 x = *(const float4*)(asrc + s * 32 + acg * 4);
      u16x4 pk;
      pk[0] = f2bf(x.x); pk[1] = f2bf(x.y); pk[2] = f2bf(x.z); pk[3] = f2bf(x.w);
      *(u16x4*)(&As[aoff]) = pk;
    }
#pragma unroll
    for (int j = 0; j < 2; ++j) {  // stage B async, pre-swizzled source
      const int rl = j * 128 + wid * 16 + (lane >> 2);
      const int gc = (lane & 3) ^ ((rl >> 1) & 3);
      const u16* src = wt + (long)rl * K + (kk * 8 + s) * 32 + gc * 8;
      u16* dst = &Bs[(j * 128 + wid * 16) * 32];
      GLOAD_LDS16(src, dst);
    }
    __syncthreads();
    bf16x8 af[2], bfv[4];
#pragma unroll
    for (int m = 0; m < 2; ++m) {
      const int r = wr * 32 + m * 16 + fr;
      u16x8 t = *(const u16x8*)(&As[r * 32 + (fq ^ ((r >> 1) & 3)) * 8]);
      af[m] = __builtin_bit_cast(bf16x8, t);
    }
#pragma unroll
    for (int n = 0; n < 4; ++n) {
      const int o = wc * 64 + n * 16 + fr;
      u16x8 t = *(const u16x8*)(&Bs[o * 32 + (fq ^ ((o >> 1) & 3)) * 8]);
      bfv[n] = __builtin_bit_cast(bf16x8, t);
    }
#pragma unroll
    for (int m = 0; m < 2; ++m)
#pragma unroll
      for (int n = 0; n < 4; ++n)
        acc[m][n] = __builtin_amdgcn_mfma_f32_16x16x32_bf16(af[m], bfv[n], acc[m][n], 0, 0, 0);
    __syncthreads();
  }
#pragma unroll
  for (int m = 0; m < 2; ++m)
#pragma unroll
    for (int reg = 0; reg < 4; ++reg) {
      const int r = row0 + wr * 32 + m * 16 + fq * 4 + reg;
#pragma unroll
      for (int n = 0; n < 4; ++n)
        To[r * 256 + wc * 64 + n * 16 + fr] = f2bf(acc[m][n][reg]);
    }
}

// ------- main: wave-per-row gather over projected tables + fused emb --------
template <int CK, int LOG2T, int S0, int OUT0>
__device__ __forceinline__ void row_gather(
    int row, int lane, const int* __restrict__ value,
    const int* __restrict__ position, const u16* __restrict__ Tp,
    const float* __restrict__ bias, float* __restrict__ out) {
  constexpr int T = 1 << LOG2T;
  const int b = row >> LOG2T, to = row & (T - 1);
  const long base = (long)b * S_TOT + S0 + to * CK;
  // wave-uniform index loads: value row is 16B-aligned, position row 8B-aligned
  int vv[CK];
  *(int4*)vv = *(const int4*)(value + base);
  if constexpr (CK == 8) *(int4*)(vv + 4) = *(const int4*)(value + base + 4);
  int pp[3 * CK];
#pragma unroll
  for (int j = 0; j < 3 * CK / 2; ++j)
    *(int2*)(pp + 2 * j) = *(const int2*)(position + base * 3 + 2 * j);

  const int o0 = lane * 4;
  const float4 bz = *(const float4*)(bias + o0);
  float s0 = bz.x, s1 = bz.y, s2 = bz.z, s3 = bz.w;
#pragma unroll
  for (int kk = 0; kk < CK; ++kk) {
    const u16* tb = Tp + kk * 65536;
    const uint2 a0 = *(const uint2*)(tb + vv[kk] * 256 + o0);
    const uint2 a1 = *(const uint2*)(tb + (4 + pp[3 * kk + 0]) * 256 + o0);
    const uint2 a2 = *(const uint2*)(tb + (68 + pp[3 * kk + 1]) * 256 + o0);
    const uint2 a3 = *(const uint2*)(tb + (132 + pp[3 * kk + 2]) * 256 + o0);
    s0 += bfl(a0.x) + bfl(a1.x) + bfl(a2.x) + bfl(a3.x);
    s1 += bfh(a0.x) + bfh(a1.x) + bfh(a2.x) + bfh(a3.x);
    s2 += bfl(a0.y) + bfl(a1.y) + bfl(a2.y) + bfl(a3.y);
    s3 += bfh(a0.y) + bfh(a1.y) + bfh(a2.y) + bfh(a3.y);
  }
  *(float4*)(out + ((long)b * OUT_T + OUT0 + to) * 256 + o0) =
      make_float4(s0, s1, s2, s3);
}

__global__ __launch_bounds__(512) void fused_main(
    const int* __restrict__ value, const int* __restrict__ depth,
    const int* __restrict__ position,
    const u16* __restrict__ T3, const float* __restrict__ b3,
    const u16* __restrict__ T4, const float* __restrict__ b4,
    const float* __restrict__ ve0, const float* __restrict__ pe0, const float* __restrict__ de0,
    const float* __restrict__ ve1, const float* __restrict__ pe1, const float* __restrict__ de1,
    const float* __restrict__ ve2, const float* __restrict__ pe2, const float* __restrict__ de2,
    float* __restrict__ out) {
  const int wid = threadIdx.x >> 6, lane = threadIdx.x & 63;
  const int bid = blockIdx.x;
  if (bid < 4096) {  // layer 4: 32768 rows, 1 row/wave
    row_gather<8, 12, 4680, 1608>(bid * 8 + wid, lane, value, position, T4, b4, out);
  } else if (bid < 5120) {  // layer 3: 8192 rows
    row_gather<4, 10, 584, 584>((bid - 4096) * 8 + wid, lane, value, position, T3, b3, out);
  } else {  // layers 0-2: 4672 tokens, 1 token/wave
    const int tok = (bid - 5120) * 8 + wid;
    const int b = tok / 584;
    const int t = tok - b * 584;
    const float *ve, *pe, *de;
    if (t < 8)       { ve = ve0; pe = pe0; de = de0; }
    else if (t < 72) { ve = ve1; pe = pe1; de = de1; }
    else             { ve = ve2; pe = pe2; de = de2; }
    const long base = (long)b * S_TOT + t;
    const int v = value[base];
    const int d = depth[base];
    const int p0 = position[base * 3 + 0];
    const int p1 = position[base * 3 + 1];
    const int p2 = position[base * 3 + 2];
    const int e = lane * 4;
    const float4 x = *(const float4*)(ve + v * EMB + e);
    const float4 y = *(const float4*)(pe + p0 * EMB + e);
    const float4 z = *(const float4*)(pe + (64 + p1) * EMB + e);
    const float4 u = *(const float4*)(pe + (128 + p2) * EMB + e);
    const float4 w = *(const float4*)(de + d * EMB + e);
    float4 r;
    r.x = x.x + y.x + z.x + u.x + w.x;
    r.y = x.y + y.y + z.y + u.y + w.y;
    r.z = x.z + y.z + z.z + u.z + w.z;
    r.w = x.w + y.w + z.w + u.w + w.w;
    *(float4*)(out + ((long)b * OUT_T + t) * EMB + e) = r;
  }
}

// ================= FALLBACK (ws too small; raw-W staging path) ==============
__global__ __launch_bounds__(256) void emb_small(
    const int* __restrict__ value, const int* __restrict__ depth,
    const int* __restrict__ position,
    const float* __restrict__ ve0, const float* __restrict__ pe0, const float* __restrict__ de0,
    const float* __restrict__ ve1, const float* __restrict__ pe1, const float* __restrict__ de1,
    const float* __restrict__ ve2, const float* __restrict__ pe2, const float* __restrict__ de2,
    float* __restrict__ out) {
  const int tok = blockIdx.x * 4 + (threadIdx.x >> 6);
  const int lane = threadIdx.x & 63;
  const int b = tok / 584;
  const int t = tok - b * 584;
  const float *ve, *pe, *de;
  if (t < 8)       { ve = ve0; pe = pe0; de = de0; }
  else if (t < 72) { ve = ve1; pe = pe1; de = de1; }
  else             { ve = ve2; pe = pe2; de = de2; }
  const long base = (long)b * S_TOT + t;
  const int v = value[base];
  const int d = depth[base];
  const int p0 = position[base * 3 + 0];
  const int p1 = position[base * 3 + 1];
  const int p2 = position[base * 3 + 2];
  const int e = lane * 4;
  const float4 x = *(const float4*)(ve + v * EMB + e);
  const float4 y = *(const float4*)(pe + p0 * EMB + e);
  const float4 z = *(const float4*)(pe + (64 + p1) * EMB + e);
  const float4 u = *(const float4*)(pe + (128 + p2) * EMB + e);
  const float4 w = *(const float4*)(de + d * EMB + e);
  float4 r;
  r.x = x.x + y.x + z.x + u.x + w.x;
  r.y = x.y + y.y + z.y + u.y + w.y;
  r.z = x.z + y.z + z.z + u.z + w.z;
  r.w = x.w + y.w + z.w + u.w + w.w;
  *(float4*)(out + ((long)b * OUT_T + t) * EMB + e) = r;
}

template <int K, int LOG2T, int CK, int S0, int OUT0>
__device__ __forceinline__ void conv_tile(
    int bid, const int* __restrict__ value, const int* __restrict__ position,
    const float* __restrict__ ve, const float* __restrict__ pe,
    const float* __restrict__ wraw, const float* __restrict__ bias,
    float* __restrict__ out,
    u16 (*As)[64 * 32], u16 (*Bs)[256 * 32], unsigned* idxc) {
  constexpr int T = 1 << LOG2T;
  constexpr int NS = K / 32;
  const int tid = threadIdx.x;
  const int lane = tid & 63;
  const int wid = tid >> 6;
  const int wr = wid >> 2;
  const int wc = wid & 3;
  const int fr = lane & 15;
  const int fq = lane >> 4;
  const int row0 = bid * 64;
  for (int e = tid; e < 64 * CK; e += 512) {
    const int r = e / CK, kk = e % CK;
    const int grow = row0 + r;
    const int b = grow >> LOG2T;
    const int to = grow & (T - 1);
    const long sidx = (long)b * S_TOT + (S0 + to * CK + kk);
    const int* pp = position + sidx * 3;
    idxc[e] = (unsigned)value[sidx] | ((unsigned)pp[0] << 8) |
              ((unsigned)pp[1] << 16) | ((unsigned)pp[2] << 24);
  }
  __syncthreads();
  const int arow = tid >> 3;
  const int acg = tid & 7;
  const int agran = acg >> 1, ahalf = acg & 1;
  const int aoff = arow * 32 + (agran ^ ((arow >> 1) & 3)) * 8 + ahalf * 4;
  auto gatherA = [&](int s, float4& r) {
    const int kk = s >> 3;
    const int e0 = (s & 7) * 32 + acg * 4;
    const unsigned q = idxc[arow * CK + kk];
    const int v = q & 255, p0 = (q >> 8) & 255, p1 = (q >> 16) & 255, p2 = q >> 24;
    float4 x = *(const float4*)(ve + v * EMB + e0);
    float4 y = *(const float4*)(pe + p0 * EMB + e0);
    float4 z = *(const float4*)(pe + (64 + p1) * EMB + e0);
    float4 u = *(const float4*)(pe + (128 + p2) * EMB + e0);
    r.x = x.x + y.x + z.x + u.x;
    r.y = x.y + y.y + z.y + u.y;
    r.z = x.z + y.z + z.z + u.z;
    r.w = x.w + y.w + z.w + u.w;
  };
  auto writeA = [&](int buf, const float4& r) {
    u16x4 p;
    p[0] = f2bf(r.x); p[1] = f2bf(r.y); p[2] = f2bf(r.z); p[3] = f2bf(r.w);
    *(u16x4*)(&As[buf][aoff]) = p;
  };
  auto issueB = [&](int s, int buf) {
    const int o = tid >> 1;
    const int hr = tid & 1;
    const int kk = s >> 3, e0 = (s & 7) * 32;
    const int osw = (o >> 1) & 3;
#pragma unroll
    for (int g2 = 0; g2 < 2; ++g2) {
      const int g = hr * 2 + g2;
      u16x8 r;
#pragma unroll
      for (int c = 0; c < 8; ++c)
        r[c] = f2bf(wraw[(long)o * (EMB * CK) + (e0 + g * 8 + c) * CK + kk]);
      *(u16x8*)(&Bs[buf][o * 32 + (g ^ osw) * 8]) = r;
    }
  };
  f32x4 acc[2][4];
#pragma unroll
  for (int m = 0; m < 2; ++m)
#pragma unroll
    for (int n = 0; n < 4; ++n) acc[m][n] = (f32x4){0.f, 0.f, 0.f, 0.f};
  {
    float4 a0;
    gatherA(0, a0);
    issueB(0, 0);
    writeA(0, a0);
  }
  __syncthreads();
  int cur = 0;
  for (int s = 0; s < NS; ++s) {
    const int nxt = cur ^ 1;
    const bool more = (s + 1 < NS);
    float4 pa;
    if (more) {
      gatherA(s + 1, pa);
      issueB(s + 1, nxt);
    }
    bf16x8 af[2], bfv[4];
#pragma unroll
    for (int m = 0; m < 2; ++m) {
      const int r = wr * 32 + m * 16 + fr;
      u16x8 t = *(const u16x8*)(&As[cur][r * 32 + (fq ^ ((r >> 1) & 3)) * 8]);
      af[m] = __builtin_bit_cast(bf16x8, t);
    }
#pragma unroll
    for (int n = 0; n < 4; ++n) {
      const int o = wc * 64 + n * 16 + fr;
      u16x8 t = *(const u16x8*)(&Bs[cur][o * 32 + (fq ^ ((o >> 1) & 3)) * 8]);
      bfv[n] = __builtin_bit_cast(bf16x8, t);
    }
#pragma unroll
    for (int m = 0; m < 2; ++m)
#pragma unroll
      for (int n = 0; n < 4; ++n)
        acc[m][n] = __builtin_amdgcn_mfma_f32_16x16x32_bf16(af[m], bfv[n], acc[m][n], 0, 0, 0);
    if (more) writeA(nxt, pa);
    __syncthreads();
    cur = nxt;
  }
  float bz[4];
#pragma unroll
  for (int n = 0; n < 4; ++n) bz[n] = bias[wc * 64 + n * 16 + fr];
#pragma unroll
  for (int m = 0; m < 2; ++m) {
#pragma unroll
    for (int reg = 0; reg < 4; ++reg) {
      const int grow = row0 + wr * 32 + m * 16 + fq * 4 + reg;
      const int bb = grow >> LOG2T;
      const int to = grow & (T - 1);
      float* op = out + ((long)bb * OUT_T + OUT0 + to) * EMB + wc * 64 + fr;
#pragma unroll
      for (int n = 0; n < 4; ++n) op[n * 16] = acc[m][n][reg] + bz[n];
    }
  }
}

__global__ __launch_bounds__(512, 4) void conv_fused(
    const int* __restrict__ value, const int* __restrict__ position,
    const float* __restrict__ ve3, const float* __restrict__ pe3,
    const float* __restrict__ w3, const float* __restrict__ b3,
    const float* __restrict__ ve4, const float* __restrict__ pe4,
    const float* __restrict__ w4, const float* __restrict__ b4,
    float* __restrict__ out) {
  __shared__ __align__(16) u16 As[2][64 * 32];
  __shared__ __align__(16) u16 Bs[2][256 * 32];
  __shared__ __align__(16) unsigned idxc[64 * 8];
  const int g = blockIdx.x / 5, r = blockIdx.x % 5;
  if (r == 0)
    conv_tile<1024, 10, 4, 584, 584>(g, value, position, ve3, pe3, w3, b3,
                                     out, As, Bs, idxc);
  else
    conv_tile<2048, 12, 8, 4680, 1608>(g * 4 + (r - 1), value, position, ve4,
                                       pe4, w4, b4, out, As, Bs, idxc);
}

extern "C" void kernel_launch(void* const* d_in, const int* in_sizes, int n_in,
                              void* d_out, int out_size, void* d_ws, size_t ws_size,
                              hipStream_t stream) {
  const int* value = (const int*)d_in[0];
  const int* depth = (const int*)d_in[1];
  const int* position = (const int*)d_in[2];
  const float* ve0 = (const float*)d_in[3];
  const float* pe0 = (const float*)d_in[4];
  const float* ve1 = (const float*)d_in[5];
  const float* pe1 = (const float*)d_in[6];
  const float* ve2 = (const float*)d_in[7];
  const float* pe2 = (const float*)d_in[8];
  const float* ve3 = (const float*)d_in[9];
  const float* pe3 = (const float*)d_in[10];
  const float* ve4 = (const float*)d_in[11];
  const float* pe4 = (const float*)d_in[12];
  const float* de0 = (const float*)d_in[13];
  const float* de1 = (const float*)d_in[14];
  const float* de2 = (const float*)d_in[15];
  const float* w3 = (const float*)d_in[16];
  const float* b3 = (const float*)d_in[17];
  const float* w4 = (const float*)d_in[18];
  const float* b4 = (const float*)d_in[19];
  float* out = (float*)d_out;

  u16* wt3 = (u16*)d_ws;
  u16* wt4 = wt3 + 256 * 1024;
  u16* T3 = wt4 + 256 * 2048;
  u16* T4 = T3 + 4 * 65536;
  const size_t need = (size_t)(256 * 1024 + 256 * 2048 + 12 * 65536) * sizeof(u16);

  if (ws_size >= need) {
    transpose_w<<<(256 * 2048) / 256, 256, 0, stream>>>(w3, w4, wt3, wt4);
    proj_tables<<<48, 512, 0, stream>>>(ve3, pe3, wt3, ve4, pe4, wt4, T3, T4);
    fused_main<<<5704, 512, 0, stream>>>(value, depth, position, T3, b3, T4, b4,
                                         ve0, pe0, de0, ve1, pe1, de1,
                                         ve2, pe2, de2, out);
  } else {
    emb_small<<<1168, 256, 0, stream>>>(value, depth, position, ve0, pe0, de0,
                                        ve1, pe1, de1, ve2, pe2, de2, out);
    conv_fused<<<640, 512, 0, stream>>>(value, position, ve3, pe3, w3, b3,
                                        ve4, pe4, w4, b4, out);
  }
}

// Round 8
// 66.110 us; speedup vs baseline: 1.5825x; 1.0110x over previous
//
#include <hip/hip_runtime.h>

#define S_TOT 37448
#define OUT_T 5704
#define EMB 256

typedef unsigned short u16;
typedef __bf16 bf16x8 __attribute__((ext_vector_type(8)));
typedef float f32x4 __attribute__((ext_vector_type(4)));
typedef float f32x2 __attribute__((ext_vector_type(2)));
typedef unsigned short u16x4 __attribute__((ext_vector_type(4)));
typedef unsigned short u16x8 __attribute__((ext_vector_type(8)));

__device__ __forceinline__ u16 f2bf(float f) {
  union { float f; unsigned int i; } v;
  v.f = f;
  unsigned int x = v.i;
  return (u16)((x + 0x7fffu + ((x >> 16) & 1u)) >> 16);
}
// unpack u32 of 2 bf16 -> f32x2 {lo, hi} (2 VALU; pairs with v_pk_add_f32)
__device__ __forceinline__ f32x2 bfp(unsigned u) {
  union { unsigned u; float f; } lo, hi;
  lo.u = u << 16;
  hi.u = u & 0xffff0000u;
  return (f32x2){lo.f, hi.f};
}

#define GLOAD_LDS16(g, l)                                                     \
  __builtin_amdgcn_global_load_lds((const __attribute__((address_space(1))) void*)(g), \
                                   (__attribute__((address_space(3))) void*)(l), 16, 0, 0)

// ------- W repack: f32 (O,E,k) -> bf16 Wt[o][kk*256+e]  (coalesced) ---------
__global__ __launch_bounds__(256) void transpose_w(
    const float* __restrict__ w3, const float* __restrict__ w4,
    u16* __restrict__ wt3, u16* __restrict__ wt4) {
  const int i = blockIdx.x * 256 + threadIdx.x;
  if (i < 256 * 1024) {
    const int o = i >> 10, c = i & 1023, kk = c >> 8, e = c & 255;
    wt3[i] = f2bf(w3[o * 1024 + e * 4 + kk]);
  }
  if (i < 256 * 2048) {
    const int o = i >> 11, c = i & 2047, kk = c >> 8, e = c & 255;
    wt4[i] = f2bf(w4[o * 2048 + e * 8 + kk]);
  }
}

// ------- Projected tables: P_kk = W_kk @ [ve; pe0; pe1; pe2] ----------------
// Rows 0..3 = ve, 4..67 = pe0, 68..131 = pe1, 132..195 = pe2 (196.. garbage).
__global__ __launch_bounds__(512) void proj_tables(
    const float* __restrict__ ve3, const float* __restrict__ pe3, const u16* __restrict__ wt3,
    const float* __restrict__ ve4, const float* __restrict__ pe4, const u16* __restrict__ wt4,
    u16* __restrict__ T3, u16* __restrict__ T4) {
  __shared__ __align__(16) u16 As[64 * 32];
  __shared__ __align__(16) u16 Bs[256 * 32];
  const int bid = blockIdx.x;  // 0..47
  const int p = bid >> 2, rb = bid & 3;
  const float *ve, *pe;
  const u16* wt;
  u16* To;
  int K, kk;
  if (p < 4) { ve = ve3; pe = pe3; wt = wt3; K = 1024; kk = p;     To = T3 + kk * 65536; }
  else       { ve = ve4; pe = pe4; wt = wt4; K = 2048; kk = p - 4; To = T4 + kk * 65536; }
  const int tid = threadIdx.x;
  const int lane = tid & 63, wid = tid >> 6;
  const int wr = wid >> 2, wc = wid & 3;
  const int fr = lane & 15, fq = lane >> 4;
  const int row0 = rb * 64;

  const int arow = tid >> 3, acg = tid & 7;
  const int agran = acg >> 1, ahalf = acg & 1;
  const int aoff = arow * 32 + (agran ^ ((arow >> 1) & 3)) * 8 + ahalf * 4;
  const int gr = row0 + arow;
  const int per = (gr - 4) < 191 ? (gr - 4) : 191;
  const float* asrc = (gr < 4) ? (ve + gr * 256) : (pe + per * 256);

  f32x4 acc[2][4];
#pragma unroll
  for (int m = 0; m < 2; ++m)
#pragma unroll
    for (int n = 0; n < 4; ++n) acc[m][n] = (f32x4){0.f, 0.f, 0.f, 0.f};

  for (int s = 0; s < 8; ++s) {
    {  // stage A (f32 table row -> bf16)
      const float4 x = *(const float4*)(asrc + s * 32 + acg * 4);
      u16x4 pk;
      pk[0] = f2bf(x.x); pk[1] = f2bf(x.y); pk[2] = f2bf(x.z); pk[3] = f2bf(x.w);
      *(u16x4*)(&As[aoff]) = pk;
    }
#pragma unroll
    for (int j = 0; j < 2; ++j) {  // stage B async, pre-swizzled source
      const int rl = j * 128 + wid * 16 + (lane >> 2);
      const int gc = (lane & 3) ^ ((rl >> 1) & 3);
      const u16* src = wt + (long)rl * K + (kk * 8 + s) * 32 + gc * 8;
      u16* dst = &Bs[(j * 128 + wid * 16) * 32];
      GLOAD_LDS16(src, dst);
    }
    __syncthreads();
    bf16x8 af[2], bfv[4];
#pragma unroll
    for (int m = 0; m < 2; ++m) {
      const int r = wr * 32 + m * 16 + fr;
      u16x8 t = *(const u16x8*)(&As[r * 32 + (fq ^ ((r >> 1) & 3)) * 8]);
      af[m] = __builtin_bit_cast(bf16x8, t);
    }
#pragma unroll
    for (int n = 0; n < 4; ++n) {
      const int o = wc * 64 + n * 16 + fr;
      u16x8 t = *(const u16x8*)(&Bs[o * 32 + (fq ^ ((o >> 1) & 3)) * 8]);
      bfv[n] = __builtin_bit_cast(bf16x8, t);
    }
#pragma unroll
    for (int m = 0; m < 2; ++m)
#pragma unroll
      for (int n = 0; n < 4; ++n)
        acc[m][n] = __builtin_amdgcn_mfma_f32_16x16x32_bf16(af[m], bfv[n], acc[m][n], 0, 0, 0);
    __syncthreads();
  }
#pragma unroll
  for (int m = 0; m < 2; ++m)
#pragma unroll
    for (int reg = 0; reg < 4; ++reg) {
      const int r = row0 + wr * 32 + m * 16 + fq * 4 + reg;
#pragma unroll
      for (int n = 0; n < 4; ++n)
        To[r * 256 + wc * 64 + n * 16 + fr] = f2bf(acc[m][n][reg]);
    }
}

// ------- main: 4 rows per wave, packed f32x2 accumulate ---------------------
template <int CK, int LOG2T, int S0, int OUT0>
__device__ __forceinline__ void row_gather(
    int row, int lane, const int* __restrict__ value,
    const int* __restrict__ position, const u16* __restrict__ Tp,
    const f32x4& bz, float* __restrict__ out) {
  constexpr int T = 1 << LOG2T;
  const int b = row >> LOG2T, to = row & (T - 1);
  const long base = (long)b * S_TOT + S0 + to * CK;
  int vv[CK];
  *(int4*)vv = *(const int4*)(value + base);
  if constexpr (CK == 8) *(int4*)(vv + 4) = *(const int4*)(value + base + 4);
  int pp[3 * CK];
#pragma unroll
  for (int j = 0; j < 3 * CK / 2; ++j)
    *(int2*)(pp + 2 * j) = *(const int2*)(position + base * 3 + 2 * j);

  const int o0 = lane * 4;
  f32x2 ac0 = (f32x2){bz[0], bz[1]};
  f32x2 ac1 = (f32x2){bz[2], bz[3]};
#pragma unroll
  for (int kk = 0; kk < CK; ++kk) {
    const u16* tb = Tp + kk * 65536;
    const uint2 a0 = *(const uint2*)(tb + vv[kk] * 256 + o0);
    const uint2 a1 = *(const uint2*)(tb + (4 + pp[3 * kk + 0]) * 256 + o0);
    const uint2 a2 = *(const uint2*)(tb + (68 + pp[3 * kk + 1]) * 256 + o0);
    const uint2 a3 = *(const uint2*)(tb + (132 + pp[3 * kk + 2]) * 256 + o0);
    ac0 += bfp(a0.x); ac1 += bfp(a0.y);
    ac0 += bfp(a1.x); ac1 += bfp(a1.y);
    ac0 += bfp(a2.x); ac1 += bfp(a2.y);
    ac0 += bfp(a3.x); ac1 += bfp(a3.y);
  }
  *(float4*)(out + ((long)b * OUT_T + OUT0 + to) * 256 + o0) =
      make_float4(ac0[0], ac0[1], ac1[0], ac1[1]);
}

// grid: [0,1024) layer4 (32 rows/block), [1024,1280) layer3, [1280,1426) emb
__global__ __launch_bounds__(512) void fused_main(
    const int* __restrict__ value, const int* __restrict__ depth,
    const int* __restrict__ position,
    const u16* __restrict__ T3, const float* __restrict__ b3,
    const u16* __restrict__ T4, const float* __restrict__ b4,
    const float* __restrict__ ve0, const float* __restrict__ pe0, const float* __restrict__ de0,
    const float* __restrict__ ve1, const float* __restrict__ pe1, const float* __restrict__ de1,
    const float* __restrict__ ve2, const float* __restrict__ pe2, const float* __restrict__ de2,
    float* __restrict__ out) {
  const int wid = threadIdx.x >> 6, lane = threadIdx.x & 63;
  const int bid = blockIdx.x;
  if (bid < 1024) {  // layer 4: 4 rows/wave
    const int row0 = bid * 32 + wid * 4;
    const int o0 = lane * 4;
    const f32x4 bz = *(const f32x4*)(b4 + o0);
#pragma unroll
    for (int rr = 0; rr < 4; ++rr)
      row_gather<8, 12, 4680, 1608>(row0 + rr, lane, value, position, T4, bz, out);
  } else if (bid < 1280) {  // layer 3: 4 rows/wave
    const int row0 = (bid - 1024) * 32 + wid * 4;
    const int o0 = lane * 4;
    const f32x4 bz = *(const f32x4*)(b3 + o0);
#pragma unroll
    for (int rr = 0; rr < 4; ++rr)
      row_gather<4, 10, 584, 584>(row0 + rr, lane, value, position, T3, bz, out);
  } else {  // layers 0-2: 4 tokens/wave (146*32 = 4672 exactly)
    const int tok0 = (bid - 1280) * 32 + wid * 4;
    const int e = lane * 4;
#pragma unroll
    for (int rr = 0; rr < 4; ++rr) {
      const int tok = tok0 + rr;
      const int b = tok / 584;
      const int t = tok - b * 584;
      const float *ve, *pe, *de;
      if (t < 8)       { ve = ve0; pe = pe0; de = de0; }
      else if (t < 72) { ve = ve1; pe = pe1; de = de1; }
      else             { ve = ve2; pe = pe2; de = de2; }
      const long base = (long)b * S_TOT + t;
      const int v = value[base];
      const int d = depth[base];
      const int p0 = position[base * 3 + 0];
      const int p1 = position[base * 3 + 1];
      const int p2 = position[base * 3 + 2];
      const float4 x = *(const float4*)(ve + v * EMB + e);
      const float4 y = *(const float4*)(pe + p0 * EMB + e);
      const float4 z = *(const float4*)(pe + (64 + p1) * EMB + e);
      const float4 u = *(const float4*)(pe + (128 + p2) * EMB + e);
      const float4 w = *(const float4*)(de + d * EMB + e);
      float4 r;
      r.x = x.x + y.x + z.x + u.x + w.x;
      r.y = x.y + y.y + z.y + u.y + w.y;
      r.z = x.z + y.z + z.z + u.z + w.z;
      r.w = x.w + y.w + z.w + u.w + w.w;
      *(float4*)(out + ((long)b * OUT_T + t) * EMB + e) = r;
    }
  }
}

// ================= FALLBACK (ws too small; raw-W staging path) ==============
__global__ __launch_bounds__(256) void emb_small(
    const int* __restrict__ value, const int* __restrict__ depth,
    const int* __restrict__ position,
    const float* __restrict__ ve0, const float* __restrict__ pe0, const float* __restrict__ de0,
    const float* __restrict__ ve1, const float* __restrict__ pe1, const float* __restrict__ de1,
    const float* __restrict__ ve2, const float* __restrict__ pe2, const float* __restrict__ de2,
    float* __restrict__ out) {
  const int tok = blockIdx.x * 4 + (threadIdx.x >> 6);
  const int lane = threadIdx.x & 63;
  const int b = tok / 584;
  const int t = tok - b * 584;
  const float *ve, *pe, *de;
  if (t < 8)       { ve = ve0; pe = pe0; de = de0; }
  else if (t < 72) { ve = ve1; pe = pe1; de = de1; }
  else             { ve = ve2; pe = pe2; de = de2; }
  const long base = (long)b * S_TOT + t;
  const int v = value[base];
  const int d = depth[base];
  const int p0 = position[base * 3 + 0];
  const int p1 = position[base * 3 + 1];
  const int p2 = position[base * 3 + 2];
  const int e = lane * 4;
  const float4 x = *(const float4*)(ve + v * EMB + e);
  const float4 y = *(const float4*)(pe + p0 * EMB + e);
  const float4 z = *(const float4*)(pe + (64 + p1) * EMB + e);
  const float4 u = *(const float4*)(pe + (128 + p2) * EMB + e);
  const float4 w = *(const float4*)(de + d * EMB + e);
  float4 r;
  r.x = x.x + y.x + z.x + u.x + w.x;
  r.y = x.y + y.y + z.y + u.y + w.y;
  r.z = x.z + y.z + z.z + u.z + w.z;
  r.w = x.w + y.w + z.w + u.w + w.w;
  *(float4*)(out + ((long)b * OUT_T + t) * EMB + e) = r;
}

template <int K, int LOG2T, int CK, int S0, int OUT0>
__device__ __forceinline__ void conv_tile(
    int bid, const int* __restrict__ value, const int* __restrict__ position,
    const float* __restrict__ ve, const float* __restrict__ pe,
    const float* __restrict__ wraw, const float* __restrict__ bias,
    float* __restrict__ out,
    u16 (*As)[64 * 32], u16 (*Bs)[256 * 32], unsigned* idxc) {
  constexpr int T = 1 << LOG2T;
  constexpr int NS = K / 32;
  const int tid = threadIdx.x;
  const int lane = tid & 63;
  const int wid = tid >> 6;
  const int wr = wid >> 2;
  const int wc = wid & 3;
  const int fr = lane & 15;
  const int fq = lane >> 4;
  const int row0 = bid * 64;
  for (int e = tid; e < 64 * CK; e += 512) {
    const int r = e / CK, kk = e % CK;
    const int grow = row0 + r;
    const int b = grow >> LOG2T;
    const int to = grow & (T - 1);
    const long sidx = (long)b * S_TOT + (S0 + to * CK + kk);
    const int* pp = position + sidx * 3;
    idxc[e] = (unsigned)value[sidx] | ((unsigned)pp[0] << 8) |
              ((unsigned)pp[1] << 16) | ((unsigned)pp[2] << 24);
  }
  __syncthreads();
  const int arow = tid >> 3;
  const int acg = tid & 7;
  const int agran = acg >> 1, ahalf = acg & 1;
  const int aoff = arow * 32 + (agran ^ ((arow >> 1) & 3)) * 8 + ahalf * 4;
  auto gatherA = [&](int s, float4& r) {
    const int kk = s >> 3;
    const int e0 = (s & 7) * 32 + acg * 4;
    const unsigned q = idxc[arow * CK + kk];
    const int v = q & 255, p0 = (q >> 8) & 255, p1 = (q >> 16) & 255, p2 = q >> 24;
    float4 x = *(const float4*)(ve + v * EMB + e0);
    float4 y = *(const float4*)(pe + p0 * EMB + e0);
    float4 z = *(const float4*)(pe + (64 + p1) * EMB + e0);
    float4 u = *(const float4*)(pe + (128 + p2) * EMB + e0);
    r.x = x.x + y.x + z.x + u.x;
    r.y = x.y + y.y + z.y + u.y;
    r.z = x.z + y.z + z.z + u.z;
    r.w = x.w + y.w + z.w + u.w;
  };
  auto writeA = [&](int buf, const float4& r) {
    u16x4 p;
    p[0] = f2bf(r.x); p[1] = f2bf(r.y); p[2] = f2bf(r.z); p[3] = f2bf(r.w);
    *(u16x4*)(&As[buf][aoff]) = p;
  };
  auto issueB = [&](int s, int buf) {
    const int o = tid >> 1;
    const int hr = tid & 1;
    const int kk = s >> 3, e0 = (s & 7) * 32;
    const int osw = (o >> 1) & 3;
#pragma unroll
    for (int g2 = 0; g2 < 2; ++g2) {
      const int g = hr * 2 + g2;
      u16x8 r;
#pragma unroll
      for (int c = 0; c < 8; ++c)
        r[c] = f2bf(wraw[(long)o * (EMB * CK) + (e0 + g * 8 + c) * CK + kk]);
      *(u16x8*)(&Bs[buf][o * 32 + (g ^ osw) * 8]) = r;
    }
  };
  f32x4 acc[2][4];
#pragma unroll
  for (int m = 0; m < 2; ++m)
#pragma unroll
    for (int n = 0; n < 4; ++n) acc[m][n] = (f32x4){0.f, 0.f, 0.f, 0.f};
  {
    float4 a0;
    gatherA(0, a0);
    issueB(0, 0);
    writeA(0, a0);
  }
  __syncthreads();
  int cur = 0;
  for (int s = 0; s < NS; ++s) {
    const int nxt = cur ^ 1;
    const bool more = (s + 1 < NS);
    float4 pa;
    if (more) {
      gatherA(s + 1, pa);
      issueB(s + 1, nxt);
    }
    bf16x8 af[2], bfv[4];
#pragma unroll
    for (int m = 0; m < 2; ++m) {
      const int r = wr * 32 + m * 16 + fr;
      u16x8 t = *(const u16x8*)(&As[cur][r * 32 + (fq ^ ((r >> 1) & 3)) * 8]);
      af[m] = __builtin_bit_cast(bf16x8, t);
    }
#pragma unroll
    for (int n = 0; n < 4; ++n) {
      const int o = wc * 64 + n * 16 + fr;
      u16x8 t = *(const u16x8*)(&Bs[cur][o * 32 + (fq ^ ((o >> 1) & 3)) * 8]);
      bfv[n] = __builtin_bit_cast(bf16x8, t);
    }
#pragma unroll
    for (int m = 0; m < 2; ++m)
#pragma unroll
      for (int n = 0; n < 4; ++n)
        acc[m][n] = __builtin_amdgcn_mfma_f32_16x16x32_bf16(af[m], bfv[n], acc[m][n], 0, 0, 0);
    if (more) writeA(nxt, pa);
    __syncthreads();
    cur = nxt;
  }
  float bz[4];
#pragma unroll
  for (int n = 0; n < 4; ++n) bz[n] = bias[wc * 64 + n * 16 + fr];
#pragma unroll
  for (int m = 0; m < 2; ++m) {
#pragma unroll
    for (int reg = 0; reg < 4; ++reg) {
      const int grow = row0 + wr * 32 + m * 16 + fq * 4 + reg;
      const int bb = grow >> LOG2T;
      const int to = grow & (T - 1);
      float* op = out + ((long)bb * OUT_T + OUT0 + to) * EMB + wc * 64 + fr;
#pragma unroll
      for (int n = 0; n < 4; ++n) op[n * 16] = acc[m][n][reg] + bz[n];
    }
  }
}

__global__ __launch_bounds__(512, 4) void conv_fused(
    const int* __restrict__ value, const int* __restrict__ position,
    const float* __restrict__ ve3, const float* __restrict__ pe3,
    const float* __restrict__ w3, const float* __restrict__ b3,
    const float* __restrict__ ve4, const float* __restrict__ pe4,
    const float* __restrict__ w4, const float* __restrict__ b4,
    float* __restrict__ out) {
  __shared__ __align__(16) u16 As[2][64 * 32];
  __shared__ __align__(16) u16 Bs[2][256 * 32];
  __shared__ __align__(16) unsigned idxc[64 * 8];
  const int g = blockIdx.x / 5, r = blockIdx.x % 5;
  if (r == 0)
    conv_tile<1024, 10, 4, 584, 584>(g, value, position, ve3, pe3, w3, b3,
                                     out, As, Bs, idxc);
  else
    conv_tile<2048, 12, 8, 4680, 1608>(g * 4 + (r - 1), value, position, ve4,
                                       pe4, w4, b4, out, As, Bs, idxc);
}

extern "C" void kernel_launch(void* const* d_in, const int* in_sizes, int n_in,
                              void* d_out, int out_size, void* d_ws, size_t ws_size,
                              hipStream_t stream) {
  const int* value = (const int*)d_in[0];
  const int* depth = (const int*)d_in[1];
  const int* position = (const int*)d_in[2];
  const float* ve0 = (const float*)d_in[3];
  const float* pe0 = (const float*)d_in[4];
  const float* ve1 = (const float*)d_in[5];
  const float* pe1 = (const float*)d_in[6];
  const float* ve2 = (const float*)d_in[7];
  const float* pe2 = (const float*)d_in[8];
  const float* ve3 = (const float*)d_in[9];
  const float* pe3 = (const float*)d_in[10];
  const float* ve4 = (const float*)d_in[11];
  const float* pe4 = (const float*)d_in[12];
  const float* de0 = (const float*)d_in[13];
  const float* de1 = (const float*)d_in[14];
  const float* de2 = (const float*)d_in[15];
  const float* w3 = (const float*)d_in[16];
  const float* b3 = (const float*)d_in[17];
  const float* w4 = (const float*)d_in[18];
  const float* b4 = (const float*)d_in[19];
  float* out = (float*)d_out;

  u16* wt3 = (u16*)d_ws;
  u16* wt4 = wt3 + 256 * 1024;
  u16* T3 = wt4 + 256 * 2048;
  u16* T4 = T3 + 4 * 65536;
  const size_t need = (size_t)(256 * 1024 + 256 * 2048 + 12 * 65536) * sizeof(u16);

  if (ws_size >= need) {
    transpose_w<<<(256 * 2048) / 256, 256, 0, stream>>>(w3, w4, wt3, wt4);
    proj_tables<<<48, 512, 0, stream>>>(ve3, pe3, wt3, ve4, pe4, wt4, T3, T4);
    fused_main<<<1426, 512, 0, stream>>>(value, depth, position, T3, b3, T4, b4,
                                         ve0, pe0, de0, ve1, pe1, de1,
                                         ve2, pe2, de2, out);
  } else {
    emb_small<<<1168, 256, 0, stream>>>(value, depth, position, ve0, pe0, de0,
                                        ve1, pe1, de1, ve2, pe2, de2, out);
    conv_fused<<<640, 512, 0, stream>>>(value, position, ve3, pe3, w3, b3,
                                        ve4, pe4, w4, b4, out);
  }
}

// Round 10
// 49.448 us; speedup vs baseline: 2.1158x; 1.3370x over previous
//
#include <hip/hip_runtime.h>

#define S_TOT 37448
#define OUT_T 5704
#define EMB 256

typedef unsigned short u16;
typedef __bf16 bf16x8 __attribute__((ext_vector_type(8)));
typedef float f32x4 __attribute__((ext_vector_type(4)));
typedef float f32x2 __attribute__((ext_vector_type(2)));
typedef unsigned short u16x4 __attribute__((ext_vector_type(4)));
typedef unsigned short u16x8 __attribute__((ext_vector_type(8)));

__device__ __forceinline__ u16 f2bf(float f) {
  union { float f; unsigned int i; } v;
  v.f = f;
  unsigned int x = v.i;
  return (u16)((x + 0x7fffu + ((x >> 16) & 1u)) >> 16);
}
// unpack u32 of 2 bf16 -> f32x2 {lo, hi} (2 VALU; pairs with v_pk_add_f32)
__device__ __forceinline__ f32x2 bfp(unsigned u) {
  union { unsigned u; float f; } lo, hi;
  lo.u = u << 16;
  hi.u = u & 0xffff0000u;
  return (f32x2){lo.f, hi.f};
}

#define GLOAD_LDS16(g, l)                                                     \
  __builtin_amdgcn_global_load_lds((const __attribute__((address_space(1))) void*)(g), \
                                   (__attribute__((address_space(3))) void*)(l), 16, 0, 0)

// ------- W repack: f32 (O,E,k) -> bf16 Wt[o][kk*256+e]  (coalesced) ---------
__global__ __launch_bounds__(256) void transpose_w(
    const float* __restrict__ w3, const float* __restrict__ w4,
    u16* __restrict__ wt3, u16* __restrict__ wt4) {
  const int i = blockIdx.x * 256 + threadIdx.x;
  if (i < 256 * 1024) {
    const int o = i >> 10, c = i & 1023, kk = c >> 8, e = c & 255;
    wt3[i] = f2bf(w3[o * 1024 + e * 4 + kk]);
  }
  if (i < 256 * 2048) {
    const int o = i >> 11, c = i & 2047, kk = c >> 8, e = c & 255;
    wt4[i] = f2bf(w4[o * 2048 + e * 8 + kk]);
  }
}

// ------- Projected tables: P_kk = W_kk @ [ve; pe0; pe1; pe2] ----------------
// Rows 0..3 = ve, 4..67 = pe0, 68..131 = pe1, 132..195 = pe2 (196.. garbage).
__global__ __launch_bounds__(512) void proj_tables(
    const float* __restrict__ ve3, const float* __restrict__ pe3, const u16* __restrict__ wt3,
    const float* __restrict__ ve4, const float* __restrict__ pe4, const u16* __restrict__ wt4,
    u16* __restrict__ T3, u16* __restrict__ T4) {
  __shared__ __align__(16) u16 As[64 * 32];
  __shared__ __align__(16) u16 Bs[256 * 32];
  const int bid = blockIdx.x;  // 0..47
  const int p = bid >> 2, rb = bid & 3;
  const float *ve, *pe;
  const u16* wt;
  u16* To;
  int K, kk;
  if (p < 4) { ve = ve3; pe = pe3; wt = wt3; K = 1024; kk = p;     To = T3 + kk * 65536; }
  else       { ve = ve4; pe = pe4; wt = wt4; K = 2048; kk = p - 4; To = T4 + kk * 65536; }
  const int tid = threadIdx.x;
  const int lane = tid & 63, wid = tid >> 6;
  const int wr = wid >> 2, wc = wid & 3;
  const int fr = lane & 15, fq = lane >> 4;
  const int row0 = rb * 64;

  const int arow = tid >> 3, acg = tid & 7;
  const int agran = acg >> 1, ahalf = acg & 1;
  const int aoff = arow * 32 + (agran ^ ((arow >> 1) & 3)) * 8 + ahalf * 4;
  const int gr = row0 + arow;
  const int per = (gr - 4) < 191 ? (gr - 4) : 191;
  const float* asrc = (gr < 4) ? (ve + gr * 256) : (pe + per * 256);

  f32x4 acc[2][4];
#pragma unroll
  for (int m = 0; m < 2; ++m)
#pragma unroll
    for (int n = 0; n < 4; ++n) acc[m][n] = (f32x4){0.f, 0.f, 0.f, 0.f};

  for (int s = 0; s < 8; ++s) {
    {  // stage A (f32 table row -> bf16)
      const float4 x = *(const float4*)(asrc + s * 32 + acg * 4);
      u16x4 pk;
      pk[0] = f2bf(x.x); pk[1] = f2bf(x.y); pk[2] = f2bf(x.z); pk[3] = f2bf(x.w);
      *(u16x4*)(&As[aoff]) = pk;
    }
#pragma unroll
    for (int j = 0; j < 2; ++j) {  // stage B async, pre-swizzled source
      const int rl = j * 128 + wid * 16 + (lane >> 2);
      const int gc = (lane & 3) ^ ((rl >> 1) & 3);
      const u16* src = wt + (long)rl * K + (kk * 8 + s) * 32 + gc * 8;
      u16* dst = &Bs[(j * 128 + wid * 16) * 32];
      GLOAD_LDS16(src, dst);
    }
    __syncthreads();
    bf16x8 af[2], bfv[4];
#pragma unroll
    for (int m = 0; m < 2; ++m) {
      const int r = wr * 32 + m * 16 + fr;
      u16x8 t = *(const u16x8*)(&As[r * 32 + (fq ^ ((r >> 1) & 3)) * 8]);
      af[m] = __builtin_bit_cast(bf16x8, t);
    }
#pragma unroll
    for (int n = 0; n < 4; ++n) {
      const int o = wc * 64 + n * 16 + fr;
      u16x8 t = *(const u16x8*)(&Bs[o * 32 + (fq ^ ((o >> 1) & 3)) * 8]);
      bfv[n] = __builtin_bit_cast(bf16x8, t);
    }
#pragma unroll
    for (int m = 0; m < 2; ++m)
#pragma unroll
      for (int n = 0; n < 4; ++n)
        acc[m][n] = __builtin_amdgcn_mfma_f32_16x16x32_bf16(af[m], bfv[n], acc[m][n], 0, 0, 0);
    __syncthreads();
  }
#pragma unroll
  for (int m = 0; m < 2; ++m)
#pragma unroll
    for (int reg = 0; reg < 4; ++reg) {
      const int r = row0 + wr * 32 + m * 16 + fq * 4 + reg;
#pragma unroll
      for (int n = 0; n < 4; ++n)
        To[r * 256 + wc * 64 + n * 16 + fr] = f2bf(acc[m][n][reg]);
    }
}

// ------- main: half-wave row pairs, batched uint4 loads ---------------------
// Lanes 0-31 handle row pair*2, lanes 32-63 row pair*2+1. Each lane owns 8
// output cols (one uint4 = 8 bf16 per table term). ALL CK*4 loads are issued
// before any accumulation (static unrolled array -> registers) to maximize
// loads-in-flight; compiler emits counted vmcnt automatically.
template <int CK, int LOG2T, int S0, int OUT0>
__device__ __forceinline__ void rowpair_gather(
    int pair, int lane, const int* __restrict__ value,
    const int* __restrict__ position, const u16* __restrict__ Tp,
    const float4& bz0, const float4& bz1, float* __restrict__ out) {
  constexpr int T = 1 << LOG2T;
  const int row = pair * 2 + (lane >> 5);
  const int l32 = lane & 31;
  const int b = row >> LOG2T, to = row & (T - 1);
  const long base = (long)b * S_TOT + S0 + to * CK;
  int vv[CK];
  *(int4*)vv = *(const int4*)(value + base);
  if constexpr (CK == 8) *(int4*)(vv + 4) = *(const int4*)(value + base + 4);
  int pp[3 * CK];
#pragma unroll
  for (int j = 0; j < 3 * CK / 2; ++j)
    *(int2*)(pp + 2 * j) = *(const int2*)(position + base * 3 + 2 * j);

  const int o0 = l32 * 8;
  f32x2 ac0 = (f32x2){bz0.x, bz0.y};
  f32x2 ac1 = (f32x2){bz0.z, bz0.w};
  f32x2 ac2 = (f32x2){bz1.x, bz1.y};
  f32x2 ac3 = (f32x2){bz1.z, bz1.w};

  uint4 A[CK][4];
#pragma unroll
  for (int kk = 0; kk < CK; ++kk) {
    const u16* tb = Tp + kk * 65536;
    A[kk][0] = *(const uint4*)(tb + vv[kk] * 256 + o0);
    A[kk][1] = *(const uint4*)(tb + (4 + pp[3 * kk + 0]) * 256 + o0);
    A[kk][2] = *(const uint4*)(tb + (68 + pp[3 * kk + 1]) * 256 + o0);
    A[kk][3] = *(const uint4*)(tb + (132 + pp[3 * kk + 2]) * 256 + o0);
  }
#pragma unroll
  for (int kk = 0; kk < CK; ++kk) {
#pragma unroll
    for (int t = 0; t < 4; ++t) {
      ac0 += bfp(A[kk][t].x);
      ac1 += bfp(A[kk][t].y);
      ac2 += bfp(A[kk][t].z);
      ac3 += bfp(A[kk][t].w);
    }
  }
  float* op = out + ((long)b * OUT_T + OUT0 + to) * 256 + o0;
  const f32x4 r0 = (f32x4){ac0[0], ac0[1], ac1[0], ac1[1]};
  const f32x4 r1 = (f32x4){ac2[0], ac2[1], ac3[0], ac3[1]};
  __builtin_nontemporal_store(r0, (f32x4*)op);
  __builtin_nontemporal_store(r1, (f32x4*)(op + 4));
}

// grid: [0,512) layer4 (8 rows/wave), [512,640) layer3, [640,786) emb
__global__ __launch_bounds__(512) void fused_main(
    const int* __restrict__ value, const int* __restrict__ depth,
    const int* __restrict__ position,
    const u16* __restrict__ T3, const float* __restrict__ b3,
    const u16* __restrict__ T4, const float* __restrict__ b4,
    const float* __restrict__ ve0, const float* __restrict__ pe0, const float* __restrict__ de0,
    const float* __restrict__ ve1, const float* __restrict__ pe1, const float* __restrict__ de1,
    const float* __restrict__ ve2, const float* __restrict__ pe2, const float* __restrict__ de2,
    float* __restrict__ out) {
  const int wid = threadIdx.x >> 6, lane = threadIdx.x & 63;
  const int bid = blockIdx.x;
  const int o0 = (lane & 31) * 8;
  if (bid < 512) {  // layer 4: 512*8 waves * 4 pairs = 32768 rows
    const int pair0 = (bid * 8 + wid) * 4;
    const float4 bz0 = *(const float4*)(b4 + o0);
    const float4 bz1 = *(const float4*)(b4 + o0 + 4);
#pragma unroll
    for (int pr = 0; pr < 4; ++pr)
      rowpair_gather<8, 12, 4680, 1608>(pair0 + pr, lane, value, position, T4,
                                        bz0, bz1, out);
  } else if (bid < 640) {  // layer 3: 128*8*4 pairs = 8192 rows
    const int pair0 = ((bid - 512) * 8 + wid) * 4;
    const float4 bz0 = *(const float4*)(b3 + o0);
    const float4 bz1 = *(const float4*)(b3 + o0 + 4);
#pragma unroll
    for (int pr = 0; pr < 4; ++pr)
      rowpair_gather<4, 10, 584, 584>(pair0 + pr, lane, value, position, T3,
                                      bz0, bz1, out);
  } else {  // layers 0-2: 146*8 waves * 4 tokens = 4672
    const int tok0 = ((bid - 640) * 8 + wid) * 4;
    const int e = lane * 4;
#pragma unroll
    for (int rr = 0; rr < 4; ++rr) {
      const int tok = tok0 + rr;
      const int b = tok / 584;
      const int t = tok - b * 584;
      const float *ve, *pe, *de;
      if (t < 8)       { ve = ve0; pe = pe0; de = de0; }
      else if (t < 72) { ve = ve1; pe = pe1; de = de1; }
      else             { ve = ve2; pe = pe2; de = de2; }
      const long base = (long)b * S_TOT + t;
      const int v = value[base];
      const int d = depth[base];
      const int p0 = position[base * 3 + 0];
      const int p1 = position[base * 3 + 1];
      const int p2 = position[base * 3 + 2];
      const float4 x = *(const float4*)(ve + v * EMB + e);
      const float4 y = *(const float4*)(pe + p0 * EMB + e);
      const float4 z = *(const float4*)(pe + (64 + p1) * EMB + e);
      const float4 u = *(const float4*)(pe + (128 + p2) * EMB + e);
      const float4 w = *(const float4*)(de + d * EMB + e);
      f32x4 r;
      r[0] = x.x + y.x + z.x + u.x + w.x;
      r[1] = x.y + y.y + z.y + u.y + w.y;
      r[2] = x.z + y.z + z.z + u.z + w.z;
      r[3] = x.w + y.w + z.w + u.w + w.w;
      __builtin_nontemporal_store(r, (f32x4*)(out + ((long)b * OUT_T + t) * EMB + e));
    }
  }
}

// ================= FALLBACK (ws too small; raw-W staging path) ==============
__global__ __launch_bounds__(256) void emb_small(
    const int* __restrict__ value, const int* __restrict__ depth,
    const int* __restrict__ position,
    const float* __restrict__ ve0, const float* __restrict__ pe0, const float* __restrict__ de0,
    const float* __restrict__ ve1, const float* __restrict__ pe1, const float* __restrict__ de1,
    const float* __restrict__ ve2, const float* __restrict__ pe2, const float* __restrict__ de2,
    float* __restrict__ out) {
  const int tok = blockIdx.x * 4 + (threadIdx.x >> 6);
  const int lane = threadIdx.x & 63;
  const int b = tok / 584;
  const int t = tok - b * 584;
  const float *ve, *pe, *de;
  if (t < 8)       { ve = ve0; pe = pe0; de = de0; }
  else if (t < 72) { ve = ve1; pe = pe1; de = de1; }
  else             { ve = ve2; pe = pe2; de = de2; }
  const long base = (long)b * S_TOT + t;
  const int v = value[base];
  const int d = depth[base];
  const int p0 = position[base * 3 + 0];
  const int p1 = position[base * 3 + 1];
  const int p2 = position[base * 3 + 2];
  const int e = lane * 4;
  const float4 x = *(const float4*)(ve + v * EMB + e);
  const float4 y = *(const float4*)(pe + p0 * EMB + e);
  const float4 z = *(const float4*)(pe + (64 + p1) * EMB + e);
  const float4 u = *(const float4*)(pe + (128 + p2) * EMB + e);
  const float4 w = *(const float4*)(de + d * EMB + e);
  float4 r;
  r.x = x.x + y.x + z.x + u.x + w.x;
  r.y = x.y + y.y + z.y + u.y + w.y;
  r.z = x.z + y.z + z.z + u.z + w.z;
  r.w = x.w + y.w + z.w + u.w + w.w;
  *(float4*)(out + ((long)b * OUT_T + t) * EMB + e) = r;
}

template <int K, int LOG2T, int CK, int S0, int OUT0>
__device__ __forceinline__ void conv_tile(
    int bid, const int* __restrict__ value, const int* __restrict__ position,
    const float* __restrict__ ve, const float* __restrict__ pe,
    const float* __restrict__ wraw, const float* __restrict__ bias,
    float* __restrict__ out,
    u16 (*As)[64 * 32], u16 (*Bs)[256 * 32], unsigned* idxc) {
  constexpr int T = 1 << LOG2T;
  constexpr int NS = K / 32;
  const int tid = threadIdx.x;
  const int lane = tid & 63;
  const int wid = tid >> 6;
  const int wr = wid >> 2;
  const int wc = wid & 3;
  const int fr = lane & 15;
  const int fq = lane >> 4;
  const int row0 = bid * 64;
  for (int e = tid; e < 64 * CK; e += 512) {
    const int r = e / CK, kk = e % CK;
    const int grow = row0 + r;
    const int b = grow >> LOG2T;
    const int to = grow & (T - 1);
    const long sidx = (long)b * S_TOT + (S0 + to * CK + kk);
    const int* pp = position + sidx * 3;
    idxc[e] = (unsigned)value[sidx] | ((unsigned)pp[0] << 8) |
              ((unsigned)pp[1] << 16) | ((unsigned)pp[2] << 24);
  }
  __syncthreads();
  const int arow = tid >> 3;
  const int acg = tid & 7;
  const int agran = acg >> 1, ahalf = acg & 1;
  const int aoff = arow * 32 + (agran ^ ((arow >> 1) & 3)) * 8 + ahalf * 4;
  auto gatherA = [&](int s, float4& r) {
    const int kk = s >> 3;
    const int e0 = (s & 7) * 32 + acg * 4;
    const unsigned q = idxc[arow * CK + kk];
    const int v = q & 255, p0 = (q >> 8) & 255, p1 = (q >> 16) & 255, p2 = q >> 24;
    float4 x = *(const float4*)(ve + v * EMB + e0);
    float4 y = *(const float4*)(pe + p0 * EMB + e0);
    float4 z = *(const float4*)(pe + (64 + p1) * EMB + e0);
    float4 u = *(const float4*)(pe + (128 + p2) * EMB + e0);
    r.x = x.x + y.x + z.x + u.x;
    r.y = x.y + y.y + z.y + u.y;
    r.z = x.z + y.z + z.z + u.z;
    r.w = x.w + y.w + z.w + u.w;
  };
  auto writeA = [&](int buf, const float4& r) {
    u16x4 p;
    p[0] = f2bf(r.x); p[1] = f2bf(r.y); p[2] = f2bf(r.z); p[3] = f2bf(r.w);
    *(u16x4*)(&As[buf][aoff]) = p;
  };
  auto issueB = [&](int s, int buf) {
    const int o = tid >> 1;
    const int hr = tid & 1;
    const int kk = s >> 3, e0 = (s & 7) * 32;
    const int osw = (o >> 1) & 3;
#pragma unroll
    for (int g2 = 0; g2 < 2; ++g2) {
      const int g = hr * 2 + g2;
      u16x8 r;
#pragma unroll
      for (int c = 0; c < 8; ++c)
        r[c] = f2bf(wraw[(long)o * (EMB * CK) + (e0 + g * 8 + c) * CK + kk]);
      *(u16x8*)(&Bs[buf][o * 32 + (g ^ osw) * 8]) = r;
    }
  };
  f32x4 acc[2][4];
#pragma unroll
  for (int m = 0; m < 2; ++m)
#pragma unroll
    for (int n = 0; n < 4; ++n) acc[m][n] = (f32x4){0.f, 0.f, 0.f, 0.f};
  {
    float4 a0;
    gatherA(0, a0);
    issueB(0, 0);
    writeA(0, a0);
  }
  __syncthreads();
  int cur = 0;
  for (int s = 0; s < NS; ++s) {
    const int nxt = cur ^ 1;
    const bool more = (s + 1 < NS);
    float4 pa;
    if (more) {
      gatherA(s + 1, pa);
      issueB(s + 1, nxt);
    }
    bf16x8 af[2], bfv[4];
#pragma unroll
    for (int m = 0; m < 2; ++m) {
      const int r = wr * 32 + m * 16 + fr;
      u16x8 t = *(const u16x8*)(&As[cur][r * 32 + (fq ^ ((r >> 1) & 3)) * 8]);
      af[m] = __builtin_bit_cast(bf16x8, t);
    }
#pragma unroll
    for (int n = 0; n < 4; ++n) {
      const int o = wc * 64 + n * 16 + fr;
      u16x8 t = *(const u16x8*)(&Bs[cur][o * 32 + (fq ^ ((o >> 1) & 3)) * 8]);
      bfv[n] = __builtin_bit_cast(bf16x8, t);
    }
#pragma unroll
    for (int m = 0; m < 2; ++m)
#pragma unroll
      for (int n = 0; n < 4; ++n)
        acc[m][n] = __builtin_amdgcn_mfma_f32_16x16x32_bf16(af[m], bfv[n], acc[m][n], 0, 0, 0);
    if (more) writeA(nxt, pa);
    __syncthreads();
    cur = nxt;
  }
  float bz[4];
#pragma unroll
  for (int n = 0; n < 4; ++n) bz[n] = bias[wc * 64 + n * 16 + fr];
#pragma unroll
  for (int m = 0; m < 2; ++m) {
#pragma unroll
    for (int reg = 0; reg < 4; ++reg) {
      const int grow = row0 + wr * 32 + m * 16 + fq * 4 + reg;
      const int bb = grow >> LOG2T;
      const int to = grow & (T - 1);
      float* op = out + ((long)bb * OUT_T + OUT0 + to) * EMB + wc * 64 + fr;
#pragma unroll
      for (int n = 0; n < 4; ++n) op[n * 16] = acc[m][n][reg] + bz[n];
    }
  }
}

__global__ __launch_bounds__(512, 4) void conv_fused(
    const int* __restrict__ value, const int* __restrict__ position,
    const float* __restrict__ ve3, const float* __restrict__ pe3,
    const float* __restrict__ w3, const float* __restrict__ b3,
    const float* __restrict__ ve4, const float* __restrict__ pe4,
    const float* __restrict__ w4, const float* __restrict__ b4,
    float* __restrict__ out) {
  __shared__ __align__(16) u16 As[2][64 * 32];
  __shared__ __align__(16) u16 Bs[2][256 * 32];
  __shared__ __align__(16) unsigned idxc[64 * 8];
  const int g = blockIdx.x / 5, r = blockIdx.x % 5;
  if (r == 0)
    conv_tile<1024, 10, 4, 584, 584>(g, value, position, ve3, pe3, w3, b3,
                                     out, As, Bs, idxc);
  else
    conv_tile<2048, 12, 8, 4680, 1608>(g * 4 + (r - 1), value, position, ve4,
                                       pe4, w4, b4, out, As, Bs, idxc);
}

extern "C" void kernel_launch(void* const* d_in, const int* in_sizes, int n_in,
                              void* d_out, int out_size, void* d_ws, size_t ws_size,
                              hipStream_t stream) {
  const int* value = (const int*)d_in[0];
  const int* depth = (const int*)d_in[1];
  const int* position = (const int*)d_in[2];
  const float* ve0 = (const float*)d_in[3];
  const float* pe0 = (const float*)d_in[4];
  const float* ve1 = (const float*)d_in[5];
  const float* pe1 = (const float*)d_in[6];
  const float* ve2 = (const float*)d_in[7];
  const float* pe2 = (const float*)d_in[8];
  const float* ve3 = (const float*)d_in[9];
  const float* pe3 = (const float*)d_in[10];
  const float* ve4 = (const float*)d_in[11];
  const float* pe4 = (const float*)d_in[12];
  const float* de0 = (const float*)d_in[13];
  const float* de1 = (const float*)d_in[14];
  const float* de2 = (const float*)d_in[15];
  const float* w3 = (const float*)d_in[16];
  const float* b3 = (const float*)d_in[17];
  const float* w4 = (const float*)d_in[18];
  const float* b4 = (const float*)d_in[19];
  float* out = (float*)d_out;

  u16* wt3 = (u16*)d_ws;
  u16* wt4 = wt3 + 256 * 1024;
  u16* T3 = wt4 + 256 * 2048;
  u16* T4 = T3 + 4 * 65536;
  const size_t need = (size_t)(256 * 1024 + 256 * 2048 + 12 * 65536) * sizeof(u16);

  if (ws_size >= need) {
    transpose_w<<<(256 * 2048) / 256, 256, 0, stream>>>(w3, w4, wt3, wt4);
    proj_tables<<<48, 512, 0, stream>>>(ve3, pe3, wt3, ve4, pe4, wt4, T3, T4);
    fused_main<<<786, 512, 0, stream>>>(value, depth, position, T3, b3, T4, b4,
                                        ve0, pe0, de0, ve1, pe1, de1,
                                        ve2, pe2, de2, out);
  } else {
    emb_small<<<1168, 256, 0, stream>>>(value, depth, position, ve0, pe0, de0,
                                        ve1, pe1, de1, ve2, pe2, de2, out);
    conv_fused<<<640, 512, 0, stream>>>(value, position, ve3, pe3, w3, b3,
                                        ve4, pe4, w4, b4, out);
  }
}

// Round 11
// 47.705 us; speedup vs baseline: 2.1931x; 1.0365x over previous
//
#include <hip/hip_runtime.h>

#define S_TOT 37448
#define OUT_T 5704
#define EMB 256

typedef unsigned short u16;
typedef __bf16 bf16x8 __attribute__((ext_vector_type(8)));
typedef float f32x4 __attribute__((ext_vector_type(4)));
typedef float f32x2 __attribute__((ext_vector_type(2)));
typedef unsigned short u16x4 __attribute__((ext_vector_type(4)));
typedef unsigned short u16x8 __attribute__((ext_vector_type(8)));

__device__ __forceinline__ u16 f2bf(float f) {
  union { float f; unsigned int i; } v;
  v.f = f;
  unsigned int x = v.i;
  return (u16)((x + 0x7fffu + ((x >> 16) & 1u)) >> 16);
}
// unpack u32 of 2 bf16 -> f32x2 {lo, hi} (2 VALU; pairs with v_pk_add_f32)
__device__ __forceinline__ f32x2 bfp(unsigned u) {
  union { unsigned u; float f; } lo, hi;
  lo.u = u << 16;
  hi.u = u & 0xffff0000u;
  return (f32x2){lo.f, hi.f};
}

#define GLOAD_LDS16(g, l)                                                     \
  __builtin_amdgcn_global_load_lds((const __attribute__((address_space(1))) void*)(g), \
                                   (__attribute__((address_space(3))) void*)(l), 16, 0, 0)

// ------- W repack: f32 (O,E,k) -> bf16 Wt[o][kk*256+e]  (coalesced) ---------
__global__ __launch_bounds__(256) void transpose_w(
    const float* __restrict__ w3, const float* __restrict__ w4,
    u16* __restrict__ wt3, u16* __restrict__ wt4) {
  const int i = blockIdx.x * 256 + threadIdx.x;
  if (i < 256 * 1024) {
    const int o = i >> 10, c = i & 1023, kk = c >> 8, e = c & 255;
    wt3[i] = f2bf(w3[o * 1024 + e * 4 + kk]);
  }
  if (i < 256 * 2048) {
    const int o = i >> 11, c = i & 2047, kk = c >> 8, e = c & 255;
    wt4[i] = f2bf(w4[o * 2048 + e * 8 + kk]);
  }
}

// ------- Projected tables: P_kk = W_kk @ [ve; pe0; pe1; pe2] ----------------
// Rows 0..3 = ve, 4..67 = pe0, 68..131 = pe1, 132..195 = pe2 (196.. garbage).
__global__ __launch_bounds__(512) void proj_tables(
    const float* __restrict__ ve3, const float* __restrict__ pe3, const u16* __restrict__ wt3,
    const float* __restrict__ ve4, const float* __restrict__ pe4, const u16* __restrict__ wt4,
    u16* __restrict__ T3, u16* __restrict__ T4) {
  __shared__ __align__(16) u16 As[64 * 32];
  __shared__ __align__(16) u16 Bs[256 * 32];
  const int bid = blockIdx.x;  // 0..47
  const int p = bid >> 2, rb = bid & 3;
  const float *ve, *pe;
  const u16* wt;
  u16* To;
  int K, kk;
  if (p < 4) { ve = ve3; pe = pe3; wt = wt3; K = 1024; kk = p;     To = T3 + kk * 65536; }
  else       { ve = ve4; pe = pe4; wt = wt4; K = 2048; kk = p - 4; To = T4 + kk * 65536; }
  const int tid = threadIdx.x;
  const int lane = tid & 63, wid = tid >> 6;
  const int wr = wid >> 2, wc = wid & 3;
  const int fr = lane & 15, fq = lane >> 4;
  const int row0 = rb * 64;

  const int arow = tid >> 3, acg = tid & 7;
  const int agran = acg >> 1, ahalf = acg & 1;
  const int aoff = arow * 32 + (agran ^ ((arow >> 1) & 3)) * 8 + ahalf * 4;
  const int gr = row0 + arow;
  const int per = (gr - 4) < 191 ? (gr - 4) : 191;
  const float* asrc = (gr < 4) ? (ve + gr * 256) : (pe + per * 256);

  f32x4 acc[2][4];
#pragma unroll
  for (int m = 0; m < 2; ++m)
#pragma unroll
    for (int n = 0; n < 4; ++n) acc[m][n] = (f32x4){0.f, 0.f, 0.f, 0.f};

  for (int s = 0; s < 8; ++s) {
    {  // stage A (f32 table row -> bf16)
      const float4 x = *(const float4*)(asrc + s * 32 + acg * 4);
      u16x4 pk;
      pk[0] = f2bf(x.x); pk[1] = f2bf(x.y); pk[2] = f2bf(x.z); pk[3] = f2bf(x.w);
      *(u16x4*)(&As[aoff]) = pk;
    }
#pragma unroll
    for (int j = 0; j < 2; ++j) {  // stage B async, pre-swizzled source
      const int rl = j * 128 + wid * 16 + (lane >> 2);
      const int gc = (lane & 3) ^ ((rl >> 1) & 3);
      const u16* src = wt + (long)rl * K + (kk * 8 + s) * 32 + gc * 8;
      u16* dst = &Bs[(j * 128 + wid * 16) * 32];
      GLOAD_LDS16(src, dst);
    }
    __syncthreads();
    bf16x8 af[2], bfv[4];
#pragma unroll
    for (int m = 0; m < 2; ++m) {
      const int r = wr * 32 + m * 16 + fr;
      u16x8 t = *(const u16x8*)(&As[r * 32 + (fq ^ ((r >> 1) & 3)) * 8]);
      af[m] = __builtin_bit_cast(bf16x8, t);
    }
#pragma unroll
    for (int n = 0; n < 4; ++n) {
      const int o = wc * 64 + n * 16 + fr;
      u16x8 t = *(const u16x8*)(&Bs[o * 32 + (fq ^ ((o >> 1) & 3)) * 8]);
      bfv[n] = __builtin_bit_cast(bf16x8, t);
    }
#pragma unroll
    for (int m = 0; m < 2; ++m)
#pragma unroll
      for (int n = 0; n < 4; ++n)
        acc[m][n] = __builtin_amdgcn_mfma_f32_16x16x32_bf16(af[m], bfv[n], acc[m][n], 0, 0, 0);
    __syncthreads();
  }
#pragma unroll
  for (int m = 0; m < 2; ++m)
#pragma unroll
    for (int reg = 0; reg < 4; ++reg) {
      const int r = row0 + wr * 32 + m * 16 + fq * 4 + reg;
#pragma unroll
      for (int n = 0; n < 4; ++n)
        To[r * 256 + wc * 64 + n * 16 + fr] = f2bf(acc[m][n][reg]);
    }
}

// ------- main: half-wave row pairs, batched uint4 loads ---------------------
template <int CK, int LOG2T, int S0, int OUT0>
__device__ __forceinline__ void rowpair_gather(
    int pair, int lane, const int* __restrict__ value,
    const int* __restrict__ position, const u16* __restrict__ Tp,
    const float4& bz0, const float4& bz1, float* __restrict__ out) {
  constexpr int T = 1 << LOG2T;
  const int row = pair * 2 + (lane >> 5);
  const int l32 = lane & 31;
  const int b = row >> LOG2T, to = row & (T - 1);
  const long base = (long)b * S_TOT + S0 + to * CK;
  int vv[CK];
  *(int4*)vv = *(const int4*)(value + base);
  if constexpr (CK == 8) *(int4*)(vv + 4) = *(const int4*)(value + base + 4);
  int pp[3 * CK];
#pragma unroll
  for (int j = 0; j < 3 * CK / 2; ++j)
    *(int2*)(pp + 2 * j) = *(const int2*)(position + base * 3 + 2 * j);

  const int o0 = l32 * 8;
  f32x2 ac0 = (f32x2){bz0.x, bz0.y};
  f32x2 ac1 = (f32x2){bz0.z, bz0.w};
  f32x2 ac2 = (f32x2){bz1.x, bz1.y};
  f32x2 ac3 = (f32x2){bz1.z, bz1.w};

  uint4 A[CK][4];
#pragma unroll
  for (int kk = 0; kk < CK; ++kk) {
    const u16* tb = Tp + kk * 65536;
    A[kk][0] = *(const uint4*)(tb + vv[kk] * 256 + o0);
    A[kk][1] = *(const uint4*)(tb + (4 + pp[3 * kk + 0]) * 256 + o0);
    A[kk][2] = *(const uint4*)(tb + (68 + pp[3 * kk + 1]) * 256 + o0);
    A[kk][3] = *(const uint4*)(tb + (132 + pp[3 * kk + 2]) * 256 + o0);
  }
#pragma unroll
  for (int kk = 0; kk < CK; ++kk) {
#pragma unroll
    for (int t = 0; t < 4; ++t) {
      ac0 += bfp(A[kk][t].x);
      ac1 += bfp(A[kk][t].y);
      ac2 += bfp(A[kk][t].z);
      ac3 += bfp(A[kk][t].w);
    }
  }
  float* op = out + ((long)b * OUT_T + OUT0 + to) * 256 + o0;
  const f32x4 r0 = (f32x4){ac0[0], ac0[1], ac1[0], ac1[1]};
  const f32x4 r1 = (f32x4){ac2[0], ac2[1], ac3[0], ac3[1]};
  __builtin_nontemporal_store(r0, (f32x4*)op);
  __builtin_nontemporal_store(r1, (f32x4*)(op + 4));
}

// grid (256 thr = 4 waves, 16 rows/block):
// [0,2048) layer4, [2048,2560) layer3, [2560,2852) emb
__global__ __launch_bounds__(256) void fused_main(
    const int* __restrict__ value, const int* __restrict__ depth,
    const int* __restrict__ position,
    const u16* __restrict__ T3, const float* __restrict__ b3,
    const u16* __restrict__ T4, const float* __restrict__ b4,
    const float* __restrict__ ve0, const float* __restrict__ pe0, const float* __restrict__ de0,
    const float* __restrict__ ve1, const float* __restrict__ pe1, const float* __restrict__ de1,
    const float* __restrict__ ve2, const float* __restrict__ pe2, const float* __restrict__ de2,
    float* __restrict__ out) {
  const int wid = threadIdx.x >> 6, lane = threadIdx.x & 63;
  const int bid = blockIdx.x;
  const int o0 = (lane & 31) * 8;
  if (bid < 2048) {  // layer 4: 2 pairs/wave = 4 rows
    const int pair0 = (bid * 4 + wid) * 2;
    const float4 bz0 = *(const float4*)(b4 + o0);
    const float4 bz1 = *(const float4*)(b4 + o0 + 4);
#pragma unroll
    for (int pr = 0; pr < 2; ++pr)
      rowpair_gather<8, 12, 4680, 1608>(pair0 + pr, lane, value, position, T4,
                                        bz0, bz1, out);
  } else if (bid < 2560) {  // layer 3: 2 pairs/wave
    const int pair0 = ((bid - 2048) * 4 + wid) * 2;
    const float4 bz0 = *(const float4*)(b3 + o0);
    const float4 bz1 = *(const float4*)(b3 + o0 + 4);
#pragma unroll
    for (int pr = 0; pr < 2; ++pr)
      rowpair_gather<4, 10, 584, 584>(pair0 + pr, lane, value, position, T3,
                                      bz0, bz1, out);
  } else {  // layers 0-2: 4 tokens/wave (292*16 = 4672 exactly)
    const int tok0 = ((bid - 2560) * 4 + wid) * 4;
    const int e = lane * 4;
#pragma unroll
    for (int rr = 0; rr < 4; ++rr) {
      const int tok = tok0 + rr;
      const int b = tok / 584;
      const int t = tok - b * 584;
      const float *ve, *pe, *de;
      if (t < 8)       { ve = ve0; pe = pe0; de = de0; }
      else if (t < 72) { ve = ve1; pe = pe1; de = de1; }
      else             { ve = ve2; pe = pe2; de = de2; }
      const long base = (long)b * S_TOT + t;
      const int v = value[base];
      const int d = depth[base];
      const int p0 = position[base * 3 + 0];
      const int p1 = position[base * 3 + 1];
      const int p2 = position[base * 3 + 2];
      const float4 x = *(const float4*)(ve + v * EMB + e);
      const float4 y = *(const float4*)(pe + p0 * EMB + e);
      const float4 z = *(const float4*)(pe + (64 + p1) * EMB + e);
      const float4 u = *(const float4*)(pe + (128 + p2) * EMB + e);
      const float4 w = *(const float4*)(de + d * EMB + e);
      f32x4 r;
      r[0] = x.x + y.x + z.x + u.x + w.x;
      r[1] = x.y + y.y + z.y + u.y + w.y;
      r[2] = x.z + y.z + z.z + u.z + w.z;
      r[3] = x.w + y.w + z.w + u.w + w.w;
      __builtin_nontemporal_store(r, (f32x4*)(out + ((long)b * OUT_T + t) * EMB + e));
    }
  }
}

// ================= FALLBACK (ws too small; raw-W staging path) ==============
__global__ __launch_bounds__(256) void emb_small(
    const int* __restrict__ value, const int* __restrict__ depth,
    const int* __restrict__ position,
    const float* __restrict__ ve0, const float* __restrict__ pe0, const float* __restrict__ de0,
    const float* __restrict__ ve1, const float* __restrict__ pe1, const float* __restrict__ de1,
    const float* __restrict__ ve2, const float* __restrict__ pe2, const float* __restrict__ de2,
    float* __restrict__ out) {
  const int tok = blockIdx.x * 4 + (threadIdx.x >> 6);
  const int lane = threadIdx.x & 63;
  const int b = tok / 584;
  const int t = tok - b * 584;
  const float *ve, *pe, *de;
  if (t < 8)       { ve = ve0; pe = pe0; de = de0; }
  else if (t < 72) { ve = ve1; pe = pe1; de = de1; }
  else             { ve = ve2; pe = pe2; de = de2; }
  const long base = (long)b * S_TOT + t;
  const int v = value[base];
  const int d = depth[base];
  const int p0 = position[base * 3 + 0];
  const int p1 = position[base * 3 + 1];
  const int p2 = position[base * 3 + 2];
  const int e = lane * 4;
  const float4 x = *(const float4*)(ve + v * EMB + e);
  const float4 y = *(const float4*)(pe + p0 * EMB + e);
  const float4 z = *(const float4*)(pe + (64 + p1) * EMB + e);
  const float4 u = *(const float4*)(pe + (128 + p2) * EMB + e);
  const float4 w = *(const float4*)(de + d * EMB + e);
  float4 r;
  r.x = x.x + y.x + z.x + u.x + w.x;
  r.y = x.y + y.y + z.y + u.y + w.y;
  r.z = x.z + y.z + z.z + u.z + w.z;
  r.w = x.w + y.w + z.w + u.w + w.w;
  *(float4*)(out + ((long)b * OUT_T + t) * EMB + e) = r;
}

template <int K, int LOG2T, int CK, int S0, int OUT0>
__device__ __forceinline__ void conv_tile(
    int bid, const int* __restrict__ value, const int* __restrict__ position,
    const float* __restrict__ ve, const float* __restrict__ pe,
    const float* __restrict__ wraw, const float* __restrict__ bias,
    float* __restrict__ out,
    u16 (*As)[64 * 32], u16 (*Bs)[256 * 32], unsigned* idxc) {
  constexpr int T = 1 << LOG2T;
  constexpr int NS = K / 32;
  const int tid = threadIdx.x;
  const int lane = tid & 63;
  const int wid = tid >> 6;
  const int wr = wid >> 2;
  const int wc = wid & 3;
  const int fr = lane & 15;
  const int fq = lane >> 4;
  const int row0 = bid * 64;
  for (int e = tid; e < 64 * CK; e += 512) {
    const int r = e / CK, kk = e % CK;
    const int grow = row0 + r;
    const int b = grow >> LOG2T;
    const int to = grow & (T - 1);
    const long sidx = (long)b * S_TOT + (S0 + to * CK + kk);
    const int* pp = position + sidx * 3;
    idxc[e] = (unsigned)value[sidx] | ((unsigned)pp[0] << 8) |
              ((unsigned)pp[1] << 16) | ((unsigned)pp[2] << 24);
  }
  __syncthreads();
  const int arow = tid >> 3;
  const int acg = tid & 7;
  const int agran = acg >> 1, ahalf = acg & 1;
  const int aoff = arow * 32 + (agran ^ ((arow >> 1) & 3)) * 8 + ahalf * 4;
  auto gatherA = [&](int s, float4& r) {
    const int kk = s >> 3;
    const int e0 = (s & 7) * 32 + acg * 4;
    const unsigned q = idxc[arow * CK + kk];
    const int v = q & 255, p0 = (q >> 8) & 255, p1 = (q >> 16) & 255, p2 = q >> 24;
    float4 x = *(const float4*)(ve + v * EMB + e0);
    float4 y = *(const float4*)(pe + p0 * EMB + e0);
    float4 z = *(const float4*)(pe + (64 + p1) * EMB + e0);
    float4 u = *(const float4*)(pe + (128 + p2) * EMB + e0);
    r.x = x.x + y.x + z.x + u.x;
    r.y = x.y + y.y + z.y + u.y;
    r.z = x.z + y.z + z.z + u.z;
    r.w = x.w + y.w + z.w + u.w;
  };
  auto writeA = [&](int buf, const float4& r) {
    u16x4 p;
    p[0] = f2bf(r.x); p[1] = f2bf(r.y); p[2] = f2bf(r.z); p[3] = f2bf(r.w);
    *(u16x4*)(&As[buf][aoff]) = p;
  };
  auto issueB = [&](int s, int buf) {
    const int o = tid >> 1;
    const int hr = tid & 1;
    const int kk = s >> 3, e0 = (s & 7) * 32;
    const int osw = (o >> 1) & 3;
#pragma unroll
    for (int g2 = 0; g2 < 2; ++g2) {
      const int g = hr * 2 + g2;
      u16x8 r;
#pragma unroll
      for (int c = 0; c < 8; ++c)
        r[c] = f2bf(wraw[(long)o * (EMB * CK) + (e0 + g * 8 + c) * CK + kk]);
      *(u16x8*)(&Bs[buf][o * 32 + (g ^ osw) * 8]) = r;
    }
  };
  f32x4 acc[2][4];
#pragma unroll
  for (int m = 0; m < 2; ++m)
#pragma unroll
    for (int n = 0; n < 4; ++n) acc[m][n] = (f32x4){0.f, 0.f, 0.f, 0.f};
  {
    float4 a0;
    gatherA(0, a0);
    issueB(0, 0);
    writeA(0, a0);
  }
  __syncthreads();
  int cur = 0;
  for (int s = 0; s < NS; ++s) {
    const int nxt = cur ^ 1;
    const bool more = (s + 1 < NS);
    float4 pa;
    if (more) {
      gatherA(s + 1, pa);
      issueB(s + 1, nxt);
    }
    bf16x8 af[2], bfv[4];
#pragma unroll
    for (int m = 0; m < 2; ++m) {
      const int r = wr * 32 + m * 16 + fr;
      u16x8 t = *(const u16x8*)(&As[cur][r * 32 + (fq ^ ((r >> 1) & 3)) * 8]);
      af[m] = __builtin_bit_cast(bf16x8, t);
    }
#pragma unroll
    for (int n = 0; n < 4; ++n) {
      const int o = wc * 64 + n * 16 + fr;
      u16x8 t = *(const u16x8*)(&Bs[cur][o * 32 + (fq ^ ((o >> 1) & 3)) * 8]);
      bfv[n] = __builtin_bit_cast(bf16x8, t);
    }
#pragma unroll
    for (int m = 0; m < 2; ++m)
#pragma unroll
      for (int n = 0; n < 4; ++n)
        acc[m][n] = __builtin_amdgcn_mfma_f32_16x16x32_bf16(af[m], bfv[n], acc[m][n], 0, 0, 0);
    if (more) writeA(nxt, pa);
    __syncthreads();
    cur = nxt;
  }
  float bz[4];
#pragma unroll
  for (int n = 0; n < 4; ++n) bz[n] = bias[wc * 64 + n * 16 + fr];
#pragma unroll
  for (int m = 0; m < 2; ++m) {
#pragma unroll
    for (int reg = 0; reg < 4; ++reg) {
      const int grow = row0 + wr * 32 + m * 16 + fq * 4 + reg;
      const int bb = grow >> LOG2T;
      const int to = grow & (T - 1);
      float* op = out + ((long)bb * OUT_T + OUT0 + to) * EMB + wc * 64 + fr;
#pragma unroll
      for (int n = 0; n < 4; ++n) op[n * 16] = acc[m][n][reg] + bz[n];
    }
  }
}

__global__ __launch_bounds__(512, 4) void conv_fused(
    const int* __restrict__ value, const int* __restrict__ position,
    const float* __restrict__ ve3, const float* __restrict__ pe3,
    const float* __restrict__ w3, const float* __restrict__ b3,
    const float* __restrict__ ve4, const float* __restrict__ pe4,
    const float* __restrict__ w4, const float* __restrict__ b4,
    float* __restrict__ out) {
  __shared__ __align__(16) u16 As[2][64 * 32];
  __shared__ __align__(16) u16 Bs[2][256 * 32];
  __shared__ __align__(16) unsigned idxc[64 * 8];
  const int g = blockIdx.x / 5, r = blockIdx.x % 5;
  if (r == 0)
    conv_tile<1024, 10, 4, 584, 584>(g, value, position, ve3, pe3, w3, b3,
                                     out, As, Bs, idxc);
  else
    conv_tile<2048, 12, 8, 4680, 1608>(g * 4 + (r - 1), value, position, ve4,
                                       pe4, w4, b4, out, As, Bs, idxc);
}

extern "C" void kernel_launch(void* const* d_in, const int* in_sizes, int n_in,
                              void* d_out, int out_size, void* d_ws, size_t ws_size,
                              hipStream_t stream) {
  const int* value = (const int*)d_in[0];
  const int* depth = (const int*)d_in[1];
  const int* position = (const int*)d_in[2];
  const float* ve0 = (const float*)d_in[3];
  const float* pe0 = (const float*)d_in[4];
  const float* ve1 = (const float*)d_in[5];
  const float* pe1 = (const float*)d_in[6];
  const float* ve2 = (const float*)d_in[7];
  const float* pe2 = (const float*)d_in[8];
  const float* ve3 = (const float*)d_in[9];
  const float* pe3 = (const float*)d_in[10];
  const float* ve4 = (const float*)d_in[11];
  const float* pe4 = (const float*)d_in[12];
  const float* de0 = (const float*)d_in[13];
  const float* de1 = (const float*)d_in[14];
  const float* de2 = (const float*)d_in[15];
  const float* w3 = (const float*)d_in[16];
  const float* b3 = (const float*)d_in[17];
  const float* w4 = (const float*)d_in[18];
  const float* b4 = (const float*)d_in[19];
  float* out = (float*)d_out;

  u16* wt3 = (u16*)d_ws;
  u16* wt4 = wt3 + 256 * 1024;
  u16* T3 = wt4 + 256 * 2048;
  u16* T4 = T3 + 4 * 65536;
  const size_t need = (size_t)(256 * 1024 + 256 * 2048 + 12 * 65536) * sizeof(u16);

  if (ws_size >= need) {
    transpose_w<<<(256 * 2048) / 256, 256, 0, stream>>>(w3, w4, wt3, wt4);
    proj_tables<<<48, 512, 0, stream>>>(ve3, pe3, wt3, ve4, pe4, wt4, T3, T4);
    fused_main<<<2852, 256, 0, stream>>>(value, depth, position, T3, b3, T4, b4,
                                         ve0, pe0, de0, ve1, pe1, de1,
                                         ve2, pe2, de2, out);
  } else {
    emb_small<<<1168, 256, 0, stream>>>(value, depth, position, ve0, pe0, de0,
                                        ve1, pe1, de1, ve2, pe2, de2, out);
    conv_fused<<<640, 512, 0, stream>>>(value, position, ve3, pe3, w3, b3,
                                        ve4, pe4, w4, b4, out);
  }
}

// Round 12
// 44.680 us; speedup vs baseline: 2.3415x; 1.0677x over previous
//
#include <hip/hip_runtime.h>

#define S_TOT 37448
#define OUT_T 5704
#define EMB 256
#define TROWS 384           // merged table rows per kk
#define TSZ (TROWS * 256)   // 98304 elems per kk

typedef unsigned short u16;
typedef __bf16 bf16x8 __attribute__((ext_vector_type(8)));
typedef float f32x4 __attribute__((ext_vector_type(4)));
typedef float f32x2 __attribute__((ext_vector_type(2)));
typedef unsigned short u16x4 __attribute__((ext_vector_type(4)));
typedef unsigned short u16x8 __attribute__((ext_vector_type(8)));

__device__ __forceinline__ u16 f2bf(float f) {
  union { float f; unsigned int i; } v;
  v.f = f;
  unsigned int x = v.i;
  return (u16)((x + 0x7fffu + ((x >> 16) & 1u)) >> 16);
}
__device__ __forceinline__ f32x2 bfp(unsigned u) {
  union { unsigned u; float f; } lo, hi;
  lo.u = u << 16;
  hi.u = u & 0xffff0000u;
  return (f32x2){lo.f, hi.f};
}

#define GLOAD_LDS16(g, l)                                                     \
  __builtin_amdgcn_global_load_lds((const __attribute__((address_space(1))) void*)(g), \
                                   (__attribute__((address_space(3))) void*)(l), 16, 0, 0)

// ------- W repack: f32 (O,E,k) -> bf16 Wt[o][kk*256+e]  (coalesced) ---------
__global__ __launch_bounds__(256) void transpose_w(
    const float* __restrict__ w3, const float* __restrict__ w4,
    u16* __restrict__ wt3, u16* __restrict__ wt4) {
  const int i = blockIdx.x * 256 + threadIdx.x;
  if (i < 256 * 1024) {
    const int o = i >> 10, c = i & 1023, kk = c >> 8, e = c & 255;
    wt3[i] = f2bf(w3[o * 1024 + e * 4 + kk]);
  }
  if (i < 256 * 2048) {
    const int o = i >> 11, c = i & 2047, kk = c >> 8, e = c & 255;
    wt4[i] = f2bf(w4[o * 2048 + e * 8 + kk]);
  }
}

// ------- Merged projected tables, per kk (TROWS=384 rows):
// rows 0..255   : U[(v<<6)|p0] = W_kk @ (ve[v] + pe0[p0])
// rows 256..319 : W_kk @ pe1[r-256]   (pe row r-192)
// rows 320..383 : W_kk @ pe2[r-320]   (pe row r-192)
// Tm layout: 12 tables of TSZ (kk 0..3 = layer3, 4..11 = layer4).
__global__ __launch_bounds__(512) void proj_tables(
    const float* __restrict__ ve3, const float* __restrict__ pe3, const u16* __restrict__ wt3,
    const float* __restrict__ ve4, const float* __restrict__ pe4, const u16* __restrict__ wt4,
    u16* __restrict__ Tm) {
  __shared__ __align__(16) u16 As[64 * 32];
  __shared__ __align__(16) u16 Bs[256 * 32];
  const int bid = blockIdx.x;  // 0..71
  const int p = bid / 6, rb = bid % 6;
  const float *ve, *pe;
  const u16* wt;
  int K, kk;
  if (p < 4) { ve = ve3; pe = pe3; wt = wt3; K = 1024; kk = p; }
  else       { ve = ve4; pe = pe4; wt = wt4; K = 2048; kk = p - 4; }
  u16* To = Tm + (long)p * TSZ;
  const int tid = threadIdx.x;
  const int lane = tid & 63, wid = tid >> 6;
  const int wr = wid >> 2, wc = wid & 3;
  const int fr = lane & 15, fq = lane >> 4;
  const int row0 = rb * 64;

  const int arow = tid >> 3, acg = tid & 7;
  const int agran = acg >> 1, ahalf = acg & 1;
  const int aoff = arow * 32 + (agran ^ ((arow >> 1) & 3)) * 8 + ahalf * 4;
  const int gr = row0 + arow;
  const bool two = (gr < 256);
  const float* s1 = two ? (ve + (gr >> 6) * 256) : (pe + (gr - 192) * 256);
  const float* s2 = two ? (pe + (gr & 63) * 256) : nullptr;

  f32x4 acc[2][4];
#pragma unroll
  for (int m = 0; m < 2; ++m)
#pragma unroll
    for (int n = 0; n < 4; ++n) acc[m][n] = (f32x4){0.f, 0.f, 0.f, 0.f};

  for (int s = 0; s < 8; ++s) {
    {  // stage A (f32 -> bf16), merged ve+pe0 rows for gr<256
      float4 x = *(const float4*)(s1 + s * 32 + acg * 4);
      if (two) {
        const float4 y = *(const float4*)(s2 + s * 32 + acg * 4);
        x.x += y.x; x.y += y.y; x.z += y.z; x.w += y.w;
      }
      u16x4 pk;
      pk[0] = f2bf(x.x); pk[1] = f2bf(x.y); pk[2] = f2bf(x.z); pk[3] = f2bf(x.w);
      *(u16x4*)(&As[aoff]) = pk;
    }
#pragma unroll
    for (int j = 0; j < 2; ++j) {  // stage B async, pre-swizzled source
      const int rl = j * 128 + wid * 16 + (lane >> 2);
      const int gc = (lane & 3) ^ ((rl >> 1) & 3);
      const u16* src = wt + (long)rl * K + (kk * 8 + s) * 32 + gc * 8;
      u16* dst = &Bs[(j * 128 + wid * 16) * 32];
      GLOAD_LDS16(src, dst);
    }
    __syncthreads();
    bf16x8 af[2], bfv[4];
#pragma unroll
    for (int m = 0; m < 2; ++m) {
      const int r = wr * 32 + m * 16 + fr;
      u16x8 t = *(const u16x8*)(&As[r * 32 + (fq ^ ((r >> 1) & 3)) * 8]);
      af[m] = __builtin_bit_cast(bf16x8, t);
    }
#pragma unroll
    for (int n = 0; n < 4; ++n) {
      const int o = wc * 64 + n * 16 + fr;
      u16x8 t = *(const u16x8*)(&Bs[o * 32 + (fq ^ ((o >> 1) & 3)) * 8]);
      bfv[n] = __builtin_bit_cast(bf16x8, t);
    }
#pragma unroll
    for (int m = 0; m < 2; ++m)
#pragma unroll
      for (int n = 0; n < 4; ++n)
        acc[m][n] = __builtin_amdgcn_mfma_f32_16x16x32_bf16(af[m], bfv[n], acc[m][n], 0, 0, 0);
    __syncthreads();
  }
#pragma unroll
  for (int m = 0; m < 2; ++m)
#pragma unroll
    for (int reg = 0; reg < 4; ++reg) {
      const int r = row0 + wr * 32 + m * 16 + fq * 4 + reg;
#pragma unroll
      for (int n = 0; n < 4; ++n)
        To[r * 256 + wc * 64 + n * 16 + fr] = f2bf(acc[m][n][reg]);
    }
}

// ------- main: half-wave row pairs, 3 batched uint4 loads per kk ------------
template <int CK, int LOG2T, int S0, int OUT0>
__device__ __forceinline__ void rowpair_gather(
    int pair, int lane, const int* __restrict__ value,
    const int* __restrict__ position, const u16* __restrict__ Tp,
    const float4& bz0, const float4& bz1, float* __restrict__ out) {
  constexpr int T = 1 << LOG2T;
  const int row = pair * 2 + (lane >> 5);
  const int l32 = lane & 31;
  const int b = row >> LOG2T, to = row & (T - 1);
  const long base = (long)b * S_TOT + S0 + to * CK;
  int vv[CK];
  *(int4*)vv = *(const int4*)(value + base);
  if constexpr (CK == 8) *(int4*)(vv + 4) = *(const int4*)(value + base + 4);
  int pp[3 * CK];
#pragma unroll
  for (int j = 0; j < 3 * CK / 2; ++j)
    *(int2*)(pp + 2 * j) = *(const int2*)(position + base * 3 + 2 * j);

  const int o0 = l32 * 8;
  f32x2 ac0 = (f32x2){bz0.x, bz0.y};
  f32x2 ac1 = (f32x2){bz0.z, bz0.w};
  f32x2 ac2 = (f32x2){bz1.x, bz1.y};
  f32x2 ac3 = (f32x2){bz1.z, bz1.w};

  uint4 A[CK][3];
#pragma unroll
  for (int kk = 0; kk < CK; ++kk) {
    const u16* tb = Tp + kk * TSZ;
    A[kk][0] = *(const uint4*)(tb + ((vv[kk] << 6) | pp[3 * kk + 0]) * 256 + o0);
    A[kk][1] = *(const uint4*)(tb + (256 + pp[3 * kk + 1]) * 256 + o0);
    A[kk][2] = *(const uint4*)(tb + (320 + pp[3 * kk + 2]) * 256 + o0);
  }
#pragma unroll
  for (int kk = 0; kk < CK; ++kk) {
#pragma unroll
    for (int t = 0; t < 3; ++t) {
      ac0 += bfp(A[kk][t].x);
      ac1 += bfp(A[kk][t].y);
      ac2 += bfp(A[kk][t].z);
      ac3 += bfp(A[kk][t].w);
    }
  }
  float* op = out + ((long)b * OUT_T + OUT0 + to) * 256 + o0;
  const f32x4 r0 = (f32x4){ac0[0], ac0[1], ac1[0], ac1[1]};
  const f32x4 r1 = (f32x4){ac2[0], ac2[1], ac3[0], ac3[1]};
  __builtin_nontemporal_store(r0, (f32x4*)op);
  __builtin_nontemporal_store(r1, (f32x4*)(op + 4));
}

// grid (256 thr = 4 waves, 16 rows/block):
// [0,2048) layer4, [2048,2560) layer3, [2560,2852) emb
__global__ __launch_bounds__(256) void fused_main(
    const int* __restrict__ value, const int* __restrict__ depth,
    const int* __restrict__ position,
    const u16* __restrict__ Tm3, const float* __restrict__ b3,
    const u16* __restrict__ Tm4, const float* __restrict__ b4,
    const float* __restrict__ ve0, const float* __restrict__ pe0, const float* __restrict__ de0,
    const float* __restrict__ ve1, const float* __restrict__ pe1, const float* __restrict__ de1,
    const float* __restrict__ ve2, const float* __restrict__ pe2, const float* __restrict__ de2,
    float* __restrict__ out) {
  const int wid = threadIdx.x >> 6, lane = threadIdx.x & 63;
  const int bid = blockIdx.x;
  const int o0 = (lane & 31) * 8;
  if (bid < 2048) {  // layer 4: 2 pairs/wave = 4 rows
    const int pair0 = (bid * 4 + wid) * 2;
    const float4 bz0 = *(const float4*)(b4 + o0);
    const float4 bz1 = *(const float4*)(b4 + o0 + 4);
#pragma unroll
    for (int pr = 0; pr < 2; ++pr)
      rowpair_gather<8, 12, 4680, 1608>(pair0 + pr, lane, value, position, Tm4,
                                        bz0, bz1, out);
  } else if (bid < 2560) {  // layer 3: 2 pairs/wave
    const int pair0 = ((bid - 2048) * 4 + wid) * 2;
    const float4 bz0 = *(const float4*)(b3 + o0);
    const float4 bz1 = *(const float4*)(b3 + o0 + 4);
#pragma unroll
    for (int pr = 0; pr < 2; ++pr)
      rowpair_gather<4, 10, 584, 584>(pair0 + pr, lane, value, position, Tm3,
                                      bz0, bz1, out);
  } else {  // layers 0-2: 4 tokens/wave (292*16 = 4672 exactly)
    const int tok0 = ((bid - 2560) * 4 + wid) * 4;
    const int e = lane * 4;
#pragma unroll
    for (int rr = 0; rr < 4; ++rr) {
      const int tok = tok0 + rr;
      const int b = tok / 584;
      const int t = tok - b * 584;
      const float *ve, *pe, *de;
      if (t < 8)       { ve = ve0; pe = pe0; de = de0; }
      else if (t < 72) { ve = ve1; pe = pe1; de = de1; }
      else             { ve = ve2; pe = pe2; de = de2; }
      const long base = (long)b * S_TOT + t;
      const int v = value[base];
      const int d = depth[base];
      const int p0 = position[base * 3 + 0];
      const int p1 = position[base * 3 + 1];
      const int p2 = position[base * 3 + 2];
      const float4 x = *(const float4*)(ve + v * EMB + e);
      const float4 y = *(const float4*)(pe + p0 * EMB + e);
      const float4 z = *(const float4*)(pe + (64 + p1) * EMB + e);
      const float4 u = *(const float4*)(pe + (128 + p2) * EMB + e);
      const float4 w = *(const float4*)(de + d * EMB + e);
      f32x4 r;
      r[0] = x.x + y.x + z.x + u.x + w.x;
      r[1] = x.y + y.y + z.y + u.y + w.y;
      r[2] = x.z + y.z + z.z + u.z + w.z;
      r[3] = x.w + y.w + z.w + u.w + w.w;
      __builtin_nontemporal_store(r, (f32x4*)(out + ((long)b * OUT_T + t) * EMB + e));
    }
  }
}

// ================= FALLBACK (ws too small; raw-W staging path) ==============
__global__ __launch_bounds__(256) void emb_small(
    const int* __restrict__ value, const int* __restrict__ depth,
    const int* __restrict__ position,
    const float* __restrict__ ve0, const float* __restrict__ pe0, const float* __restrict__ de0,
    const float* __restrict__ ve1, const float* __restrict__ pe1, const float* __restrict__ de1,
    const float* __restrict__ ve2, const float* __restrict__ pe2, const float* __restrict__ de2,
    float* __restrict__ out) {
  const int tok = blockIdx.x * 4 + (threadIdx.x >> 6);
  const int lane = threadIdx.x & 63;
  const int b = tok / 584;
  const int t = tok - b * 584;
  const float *ve, *pe, *de;
  if (t < 8)       { ve = ve0; pe = pe0; de = de0; }
  else if (t < 72) { ve = ve1; pe = pe1; de = de1; }
  else             { ve = ve2; pe = pe2; de = de2; }
  const long base = (long)b * S_TOT + t;
  const int v = value[base];
  const int d = depth[base];
  const int p0 = position[base * 3 + 0];
  const int p1 = position[base * 3 + 1];
  const int p2 = position[base * 3 + 2];
  const int e = lane * 4;
  const float4 x = *(const float4*)(ve + v * EMB + e);
  const float4 y = *(const float4*)(pe + p0 * EMB + e);
  const float4 z = *(const float4*)(pe + (64 + p1) * EMB + e);
  const float4 u = *(const float4*)(pe + (128 + p2) * EMB + e);
  const float4 w = *(const float4*)(de + d * EMB + e);
  float4 r;
  r.x = x.x + y.x + z.x + u.x + w.x;
  r.y = x.y + y.y + z.y + u.y + w.y;
  r.z = x.z + y.z + z.z + u.z + w.z;
  r.w = x.w + y.w + z.w + u.w + w.w;
  *(float4*)(out + ((long)b * OUT_T + t) * EMB + e) = r;
}

template <int K, int LOG2T, int CK, int S0, int OUT0>
__device__ __forceinline__ void conv_tile(
    int bid, const int* __restrict__ value, const int* __restrict__ position,
    const float* __restrict__ ve, const float* __restrict__ pe,
    const float* __restrict__ wraw, const float* __restrict__ bias,
    float* __restrict__ out,
    u16 (*As)[64 * 32], u16 (*Bs)[256 * 32], unsigned* idxc) {
  constexpr int T = 1 << LOG2T;
  constexpr int NS = K / 32;
  const int tid = threadIdx.x;
  const int lane = tid & 63;
  const int wid = tid >> 6;
  const int wr = wid >> 2;
  const int wc = wid & 3;
  const int fr = lane & 15;
  const int fq = lane >> 4;
  const int row0 = bid * 64;
  for (int e = tid; e < 64 * CK; e += 512) {
    const int r = e / CK, kk = e % CK;
    const int grow = row0 + r;
    const int b = grow >> LOG2T;
    const int to = grow & (T - 1);
    const long sidx = (long)b * S_TOT + (S0 + to * CK + kk);
    const int* pp = position + sidx * 3;
    idxc[e] = (unsigned)value[sidx] | ((unsigned)pp[0] << 8) |
              ((unsigned)pp[1] << 16) | ((unsigned)pp[2] << 24);
  }
  __syncthreads();
  const int arow = tid >> 3;
  const int acg = tid & 7;
  const int agran = acg >> 1, ahalf = acg & 1;
  const int aoff = arow * 32 + (agran ^ ((arow >> 1) & 3)) * 8 + ahalf * 4;
  auto gatherA = [&](int s, float4& r) {
    const int kk = s >> 3;
    const int e0 = (s & 7) * 32 + acg * 4;
    const unsigned q = idxc[arow * CK + kk];
    const int v = q & 255, p0 = (q >> 8) & 255, p1 = (q >> 16) & 255, p2 = q >> 24;
    float4 x = *(const float4*)(ve + v * EMB + e0);
    float4 y = *(const float4*)(pe + p0 * EMB + e0);
    float4 z = *(const float4*)(pe + (64 + p1) * EMB + e0);
    float4 u = *(const float4*)(pe + (128 + p2) * EMB + e0);
    r.x = x.x + y.x + z.x + u.x;
    r.y = x.y + y.y + z.y + u.y;
    r.z = x.z + y.z + z.z + u.z;
    r.w = x.w + y.w + z.w + u.w;
  };
  auto writeA = [&](int buf, const float4& r) {
    u16x4 p;
    p[0] = f2bf(r.x); p[1] = f2bf(r.y); p[2] = f2bf(r.z); p[3] = f2bf(r.w);
    *(u16x4*)(&As[buf][aoff]) = p;
  };
  auto issueB = [&](int s, int buf) {
    const int o = tid >> 1;
    const int hr = tid & 1;
    const int kk = s >> 3, e0 = (s & 7) * 32;
    const int osw = (o >> 1) & 3;
#pragma unroll
    for (int g2 = 0; g2 < 2; ++g2) {
      const int g = hr * 2 + g2;
      u16x8 r;
#pragma unroll
      for (int c = 0; c < 8; ++c)
        r[c] = f2bf(wraw[(long)o * (EMB * CK) + (e0 + g * 8 + c) * CK + kk]);
      *(u16x8*)(&Bs[buf][o * 32 + (g ^ osw) * 8]) = r;
    }
  };
  f32x4 acc[2][4];
#pragma unroll
  for (int m = 0; m < 2; ++m)
#pragma unroll
    for (int n = 0; n < 4; ++n) acc[m][n] = (f32x4){0.f, 0.f, 0.f, 0.f};
  {
    float4 a0;
    gatherA(0, a0);
    issueB(0, 0);
    writeA(0, a0);
  }
  __syncthreads();
  int cur = 0;
  for (int s = 0; s < NS; ++s) {
    const int nxt = cur ^ 1;
    const bool more = (s + 1 < NS);
    float4 pa;
    if (more) {
      gatherA(s + 1, pa);
      issueB(s + 1, nxt);
    }
    bf16x8 af[2], bfv[4];
#pragma unroll
    for (int m = 0; m < 2; ++m) {
      const int r = wr * 32 + m * 16 + fr;
      u16x8 t = *(const u16x8*)(&As[cur][r * 32 + (fq ^ ((r >> 1) & 3)) * 8]);
      af[m] = __builtin_bit_cast(bf16x8, t);
    }
#pragma unroll
    for (int n = 0; n < 4; ++n) {
      const int o = wc * 64 + n * 16 + fr;
      u16x8 t = *(const u16x8*)(&Bs[cur][o * 32 + (fq ^ ((o >> 1) & 3)) * 8]);
      bfv[n] = __builtin_bit_cast(bf16x8, t);
    }
#pragma unroll
    for (int m = 0; m < 2; ++m)
#pragma unroll
      for (int n = 0; n < 4; ++n)
        acc[m][n] = __builtin_amdgcn_mfma_f32_16x16x32_bf16(af[m], bfv[n], acc[m][n], 0, 0, 0);
    if (more) writeA(nxt, pa);
    __syncthreads();
    cur = nxt;
  }
  float bz[4];
#pragma unroll
  for (int n = 0; n < 4; ++n) bz[n] = bias[wc * 64 + n * 16 + fr];
#pragma unroll
  for (int m = 0; m < 2; ++m) {
#pragma unroll
    for (int reg = 0; reg < 4; ++reg) {
      const int grow = row0 + wr * 32 + m * 16 + fq * 4 + reg;
      const int bb = grow >> LOG2T;
      const int to = grow & (T - 1);
      float* op = out + ((long)bb * OUT_T + OUT0 + to) * EMB + wc * 64 + fr;
#pragma unroll
      for (int n = 0; n < 4; ++n) op[n * 16] = acc[m][n][reg] + bz[n];
    }
  }
}

__global__ __launch_bounds__(512, 4) void conv_fused(
    const int* __restrict__ value, const int* __restrict__ position,
    const float* __restrict__ ve3, const float* __restrict__ pe3,
    const float* __restrict__ w3, const float* __restrict__ b3,
    const float* __restrict__ ve4, const float* __restrict__ pe4,
    const float* __restrict__ w4, const float* __restrict__ b4,
    float* __restrict__ out) {
  __shared__ __align__(16) u16 As[2][64 * 32];
  __shared__ __align__(16) u16 Bs[2][256 * 32];
  __shared__ __align__(16) unsigned idxc[64 * 8];
  const int g = blockIdx.x / 5, r = blockIdx.x % 5;
  if (r == 0)
    conv_tile<1024, 10, 4, 584, 584>(g, value, position, ve3, pe3, w3, b3,
                                     out, As, Bs, idxc);
  else
    conv_tile<2048, 12, 8, 4680, 1608>(g * 4 + (r - 1), value, position, ve4,
                                       pe4, w4, b4, out, As, Bs, idxc);
}

extern "C" void kernel_launch(void* const* d_in, const int* in_sizes, int n_in,
                              void* d_out, int out_size, void* d_ws, size_t ws_size,
                              hipStream_t stream) {
  const int* value = (const int*)d_in[0];
  const int* depth = (const int*)d_in[1];
  const int* position = (const int*)d_in[2];
  const float* ve0 = (const float*)d_in[3];
  const float* pe0 = (const float*)d_in[4];
  const float* ve1 = (const float*)d_in[5];
  const float* pe1 = (const float*)d_in[6];
  const float* ve2 = (const float*)d_in[7];
  const float* pe2 = (const float*)d_in[8];
  const float* ve3 = (const float*)d_in[9];
  const float* pe3 = (const float*)d_in[10];
  const float* ve4 = (const float*)d_in[11];
  const float* pe4 = (const float*)d_in[12];
  const float* de0 = (const float*)d_in[13];
  const float* de1 = (const float*)d_in[14];
  const float* de2 = (const float*)d_in[15];
  const float* w3 = (const float*)d_in[16];
  const float* b3 = (const float*)d_in[17];
  const float* w4 = (const float*)d_in[18];
  const float* b4 = (const float*)d_in[19];
  float* out = (float*)d_out;

  u16* wt3 = (u16*)d_ws;
  u16* wt4 = wt3 + 256 * 1024;
  u16* Tm = wt4 + 256 * 2048;
  const size_t need = (size_t)(256 * 1024 + 256 * 2048 + 12 * TSZ) * sizeof(u16);

  if (ws_size >= need) {
    transpose_w<<<(256 * 2048) / 256, 256, 0, stream>>>(w3, w4, wt3, wt4);
    proj_tables<<<72, 512, 0, stream>>>(ve3, pe3, wt3, ve4, pe4, wt4, Tm);
    fused_main<<<2852, 256, 0, stream>>>(value, depth, position,
                                         Tm, b3, Tm + 4 * TSZ, b4,
                                         ve0, pe0, de0, ve1, pe1, de1,
                                         ve2, pe2, de2, out);
  } else {
    emb_small<<<1168, 256, 0, stream>>>(value, depth, position, ve0, pe0, de0,
                                        ve1, pe1, de1, ve2, pe2, de2, out);
    conv_fused<<<640, 512, 0, stream>>>(value, position, ve3, pe3, w3, b3,
                                        ve4, pe4, w4, b4, out);
  }
}

// Round 13
// 44.521 us; speedup vs baseline: 2.3499x; 1.0036x over previous
//
#include <hip/hip_runtime.h>

#define S_TOT 37448
#define OUT_T 5704
#define EMB 256
#define TROWS 384           // merged table rows per kk
#define TSZ (TROWS * 256)   // elems per kk table

typedef unsigned short u16;
typedef __bf16 bf16x8 __attribute__((ext_vector_type(8)));
typedef float f32x4 __attribute__((ext_vector_type(4)));
typedef float f32x2 __attribute__((ext_vector_type(2)));
typedef unsigned short u16x4 __attribute__((ext_vector_type(4)));
typedef unsigned short u16x8 __attribute__((ext_vector_type(8)));

__device__ __forceinline__ u16 f2bf(float f) {
  union { float f; unsigned int i; } v;
  v.f = f;
  unsigned int x = v.i;
  return (u16)((x + 0x7fffu + ((x >> 16) & 1u)) >> 16);
}
__device__ __forceinline__ f32x2 bfp(unsigned u) {
  union { unsigned u; float f; } lo, hi;
  lo.u = u << 16;
  hi.u = u & 0xffff0000u;
  return (f32x2){lo.f, hi.f};
}

#define GLOAD_LDS16(g, l)                                                     \
  __builtin_amdgcn_global_load_lds((const __attribute__((address_space(1))) void*)(g), \
                                   (__attribute__((address_space(3))) void*)(l), 16, 0, 0)

// ------- W repack: f32 (O,E,k) -> bf16 Wt[o][kk*256+e]  (coalesced) ---------
__global__ __launch_bounds__(256) void transpose_w(
    const float* __restrict__ w3, const float* __restrict__ w4,
    u16* __restrict__ wt3, u16* __restrict__ wt4) {
  const int i = blockIdx.x * 256 + threadIdx.x;
  if (i < 256 * 1024) {
    const int o = i >> 10, c = i & 1023, kk = c >> 8, e = c & 255;
    wt3[i] = f2bf(w3[o * 1024 + e * 4 + kk]);
  }
  if (i < 256 * 2048) {
    const int o = i >> 11, c = i & 2047, kk = c >> 8, e = c & 255;
    wt4[i] = f2bf(w4[o * 2048 + e * 8 + kk]);
  }
}

// ------- Merged projected tables, per kk (TROWS=384 rows):
// rows 0..255   : W_kk @ (ve[v] + pe0[p0])   at row (v<<6)|p0
// rows 256..319 : W_kk @ pe1[r-256]          (pe row r-192)
// rows 320..383 : W_kk @ pe2[r-320]          (pe row r-192)
// Grid: 144 blocks = p(12) x rb(6) x cb(2); block = 64 rows x 128 cols, 256thr.
__global__ __launch_bounds__(256) void proj_tables(
    const float* __restrict__ ve3, const float* __restrict__ pe3, const u16* __restrict__ wt3,
    const float* __restrict__ ve4, const float* __restrict__ pe4, const u16* __restrict__ wt4,
    u16* __restrict__ Tm) {
  __shared__ __align__(16) u16 As[64 * 32];
  __shared__ __align__(16) u16 Bs[128 * 32];
  const int bid = blockIdx.x;        // 0..143
  const int p = bid / 12;            // table index 0..11
  const int rcb = bid % 12;
  const int rb = rcb >> 1, cb = rcb & 1;
  const float *ve, *pe;
  const u16* wt;
  int K, kk;
  if (p < 4) { ve = ve3; pe = pe3; wt = wt3; K = 1024; kk = p; }
  else       { ve = ve4; pe = pe4; wt = wt4; K = 2048; kk = p - 4; }
  u16* To = Tm + (long)p * TSZ;
  const int tid = threadIdx.x;
  const int lane = tid & 63, wid = tid >> 6;   // 4 waves
  const int wr = wid >> 1, wc = wid & 1;       // 2x2 wave grid (32r x 64c)
  const int fr = lane & 15, fq = lane >> 4;
  const int row0 = rb * 64;

  // A staging: 8 elems/thread (64 x 32), XOR granule swizzle
  const int arow = tid >> 2, acg = tid & 3;
  const int aoff = arow * 32 + (acg ^ ((arow >> 1) & 3)) * 8;
  const int gr = row0 + arow;
  const bool two = (gr < 256);
  const float* s1 = two ? (ve + (gr >> 6) * 256) : (pe + (gr - 192) * 256);
  const float* s2 = two ? (pe + (gr & 63) * 256) : nullptr;

  f32x4 acc[2][4];
#pragma unroll
  for (int m = 0; m < 2; ++m)
#pragma unroll
    for (int n = 0; n < 4; ++n) acc[m][n] = (f32x4){0.f, 0.f, 0.f, 0.f};

  for (int s = 0; s < 8; ++s) {
    {  // stage A (merged f32 rows -> bf16)
      float4 x0 = *(const float4*)(s1 + s * 32 + acg * 8);
      float4 x1 = *(const float4*)(s1 + s * 32 + acg * 8 + 4);
      if (two) {
        const float4 y0 = *(const float4*)(s2 + s * 32 + acg * 8);
        const float4 y1 = *(const float4*)(s2 + s * 32 + acg * 8 + 4);
        x0.x += y0.x; x0.y += y0.y; x0.z += y0.z; x0.w += y0.w;
        x1.x += y1.x; x1.y += y1.y; x1.z += y1.z; x1.w += y1.w;
      }
      u16x8 pk;
      pk[0] = f2bf(x0.x); pk[1] = f2bf(x0.y); pk[2] = f2bf(x0.z); pk[3] = f2bf(x0.w);
      pk[4] = f2bf(x1.x); pk[5] = f2bf(x1.y); pk[6] = f2bf(x1.z); pk[7] = f2bf(x1.w);
      *(u16x8*)(&As[aoff]) = pk;
    }
#pragma unroll
    for (int j = 0; j < 2; ++j) {  // stage B async: 128 rows x 32 cols
      const int rloc = j * 64 + wid * 16 + (lane >> 2);
      const int gc = (lane & 3) ^ ((rloc >> 1) & 3);  // pre-swizzled SOURCE
      const u16* src = wt + (long)(cb * 128 + rloc) * K + (kk * 8 + s) * 32 + gc * 8;
      u16* dst = &Bs[(j * 64 + wid * 16) * 32];       // linear dest
      GLOAD_LDS16(src, dst);
    }
    __syncthreads();
    bf16x8 af[2], bfv[4];
#pragma unroll
    for (int m = 0; m < 2; ++m) {
      const int r = wr * 32 + m * 16 + fr;
      u16x8 t = *(const u16x8*)(&As[r * 32 + (fq ^ ((r >> 1) & 3)) * 8]);
      af[m] = __builtin_bit_cast(bf16x8, t);
    }
#pragma unroll
    for (int n = 0; n < 4; ++n) {
      const int o = wc * 64 + n * 16 + fr;
      u16x8 t = *(const u16x8*)(&Bs[o * 32 + (fq ^ ((o >> 1) & 3)) * 8]);
      bfv[n] = __builtin_bit_cast(bf16x8, t);
    }
#pragma unroll
    for (int m = 0; m < 2; ++m)
#pragma unroll
      for (int n = 0; n < 4; ++n)
        acc[m][n] = __builtin_amdgcn_mfma_f32_16x16x32_bf16(af[m], bfv[n], acc[m][n], 0, 0, 0);
    __syncthreads();
  }
#pragma unroll
  for (int m = 0; m < 2; ++m)
#pragma unroll
    for (int reg = 0; reg < 4; ++reg) {
      const int r = row0 + wr * 32 + m * 16 + fq * 4 + reg;
#pragma unroll
      for (int n = 0; n < 4; ++n)
        To[r * 256 + cb * 128 + wc * 64 + n * 16 + fr] = f2bf(acc[m][n][reg]);
    }
}

// ------- main: wave quad (4 rows) with both pairs' loads issued early -------
template <int CK, int LOG2T, int S0, int OUT0>
__device__ __forceinline__ void rowquad_gather(
    int pair0, int lane, const int* __restrict__ value,
    const int* __restrict__ position, const u16* __restrict__ Tp,
    const float4& bz0, const float4& bz1, float* __restrict__ out) {
  constexpr int T = 1 << LOG2T;
  const int l32 = lane & 31;
  const int o0 = l32 * 8;
  const int rowA = pair0 * 2 + (lane >> 5);
  const int rowB = rowA + 2;

  // --- index loads for BOTH rows up front ---
  const int bA = rowA >> LOG2T, toA = rowA & (T - 1);
  const int bB = rowB >> LOG2T, toB = rowB & (T - 1);
  const long baseA = (long)bA * S_TOT + S0 + toA * CK;
  const long baseB = (long)bB * S_TOT + S0 + toB * CK;
  int vvA[CK], vvB[CK];
  *(int4*)vvA = *(const int4*)(value + baseA);
  *(int4*)vvB = *(const int4*)(value + baseB);
  if constexpr (CK == 8) {
    *(int4*)(vvA + 4) = *(const int4*)(value + baseA + 4);
    *(int4*)(vvB + 4) = *(const int4*)(value + baseB + 4);
  }
  int ppA[3 * CK], ppB[3 * CK];
#pragma unroll
  for (int j = 0; j < 3 * CK / 2; ++j) {
    *(int2*)(ppA + 2 * j) = *(const int2*)(position + baseA * 3 + 2 * j);
    *(int2*)(ppB + 2 * j) = *(const int2*)(position + baseB * 3 + 2 * j);
  }

  // --- batched table loads for BOTH rows ---
  uint4 A[CK][3], B[CK][3];
#pragma unroll
  for (int kk = 0; kk < CK; ++kk) {
    const u16* tb = Tp + kk * TSZ;
    A[kk][0] = *(const uint4*)(tb + ((vvA[kk] << 6) | ppA[3 * kk + 0]) * 256 + o0);
    A[kk][1] = *(const uint4*)(tb + (256 + ppA[3 * kk + 1]) * 256 + o0);
    A[kk][2] = *(const uint4*)(tb + (320 + ppA[3 * kk + 2]) * 256 + o0);
  }
#pragma unroll
  for (int kk = 0; kk < CK; ++kk) {
    const u16* tb = Tp + kk * TSZ;
    B[kk][0] = *(const uint4*)(tb + ((vvB[kk] << 6) | ppB[3 * kk + 0]) * 256 + o0);
    B[kk][1] = *(const uint4*)(tb + (256 + ppB[3 * kk + 1]) * 256 + o0);
    B[kk][2] = *(const uint4*)(tb + (320 + ppB[3 * kk + 2]) * 256 + o0);
  }

  // --- accumulate + store row A ---
  {
    f32x2 ac0 = (f32x2){bz0.x, bz0.y};
    f32x2 ac1 = (f32x2){bz0.z, bz0.w};
    f32x2 ac2 = (f32x2){bz1.x, bz1.y};
    f32x2 ac3 = (f32x2){bz1.z, bz1.w};
#pragma unroll
    for (int kk = 0; kk < CK; ++kk)
#pragma unroll
      for (int t = 0; t < 3; ++t) {
        ac0 += bfp(A[kk][t].x);
        ac1 += bfp(A[kk][t].y);
        ac2 += bfp(A[kk][t].z);
        ac3 += bfp(A[kk][t].w);
      }
    float* op = out + ((long)bA * OUT_T + OUT0 + toA) * 256 + o0;
    const f32x4 r0 = (f32x4){ac0[0], ac0[1], ac1[0], ac1[1]};
    const f32x4 r1 = (f32x4){ac2[0], ac2[1], ac3[0], ac3[1]};
    __builtin_nontemporal_store(r0, (f32x4*)op);
    __builtin_nontemporal_store(r1, (f32x4*)(op + 4));
  }
  // --- accumulate + store row B ---
  {
    f32x2 ac0 = (f32x2){bz0.x, bz0.y};
    f32x2 ac1 = (f32x2){bz0.z, bz0.w};
    f32x2 ac2 = (f32x2){bz1.x, bz1.y};
    f32x2 ac3 = (f32x2){bz1.z, bz1.w};
#pragma unroll
    for (int kk = 0; kk < CK; ++kk)
#pragma unroll
      for (int t = 0; t < 3; ++t) {
        ac0 += bfp(B[kk][t].x);
        ac1 += bfp(B[kk][t].y);
        ac2 += bfp(B[kk][t].z);
        ac3 += bfp(B[kk][t].w);
      }
    float* op = out + ((long)bB * OUT_T + OUT0 + toB) * 256 + o0;
    const f32x4 r0 = (f32x4){ac0[0], ac0[1], ac1[0], ac1[1]};
    const f32x4 r1 = (f32x4){ac2[0], ac2[1], ac3[0], ac3[1]};
    __builtin_nontemporal_store(r0, (f32x4*)op);
    __builtin_nontemporal_store(r1, (f32x4*)(op + 4));
  }
}

// grid (256 thr = 4 waves, 16 rows/block):
// [0,2048) layer4, [2048,2560) layer3, [2560,2852) emb
__global__ __launch_bounds__(256) void fused_main(
    const int* __restrict__ value, const int* __restrict__ depth,
    const int* __restrict__ position,
    const u16* __restrict__ Tm3, const float* __restrict__ b3,
    const u16* __restrict__ Tm4, const float* __restrict__ b4,
    const float* __restrict__ ve0, const float* __restrict__ pe0, const float* __restrict__ de0,
    const float* __restrict__ ve1, const float* __restrict__ pe1, const float* __restrict__ de1,
    const float* __restrict__ ve2, const float* __restrict__ pe2, const float* __restrict__ de2,
    float* __restrict__ out) {
  const int wid = threadIdx.x >> 6, lane = threadIdx.x & 63;
  const int bid = blockIdx.x;
  const int o0 = (lane & 31) * 8;
  if (bid < 2048) {  // layer 4: quad (4 rows) per wave
    const int pair0 = (bid * 4 + wid) * 2;
    const float4 bz0 = *(const float4*)(b4 + o0);
    const float4 bz1 = *(const float4*)(b4 + o0 + 4);
    rowquad_gather<8, 12, 4680, 1608>(pair0, lane, value, position, Tm4,
                                      bz0, bz1, out);
  } else if (bid < 2560) {  // layer 3
    const int pair0 = ((bid - 2048) * 4 + wid) * 2;
    const float4 bz0 = *(const float4*)(b3 + o0);
    const float4 bz1 = *(const float4*)(b3 + o0 + 4);
    rowquad_gather<4, 10, 584, 584>(pair0, lane, value, position, Tm3,
                                    bz0, bz1, out);
  } else {  // layers 0-2: 4 tokens/wave (292*16 = 4672 exactly)
    const int tok0 = ((bid - 2560) * 4 + wid) * 4;
    const int e = lane * 4;
#pragma unroll
    for (int rr = 0; rr < 4; ++rr) {
      const int tok = tok0 + rr;
      const int b = tok / 584;
      const int t = tok - b * 584;
      const float *ve, *pe, *de;
      if (t < 8)       { ve = ve0; pe = pe0; de = de0; }
      else if (t < 72) { ve = ve1; pe = pe1; de = de1; }
      else             { ve = ve2; pe = pe2; de = de2; }
      const long base = (long)b * S_TOT + t;
      const int v = value[base];
      const int d = depth[base];
      const int p0 = position[base * 3 + 0];
      const int p1 = position[base * 3 + 1];
      const int p2 = position[base * 3 + 2];
      const float4 x = *(const float4*)(ve + v * EMB + e);
      const float4 y = *(const float4*)(pe + p0 * EMB + e);
      const float4 z = *(const float4*)(pe + (64 + p1) * EMB + e);
      const float4 u = *(const float4*)(pe + (128 + p2) * EMB + e);
      const float4 w = *(const float4*)(de + d * EMB + e);
      f32x4 r;
      r[0] = x.x + y.x + z.x + u.x + w.x;
      r[1] = x.y + y.y + z.y + u.y + w.y;
      r[2] = x.z + y.z + z.z + u.z + w.z;
      r[3] = x.w + y.w + z.w + u.w + w.w;
      __builtin_nontemporal_store(r, (f32x4*)(out + ((long)b * OUT_T + t) * EMB + e));
    }
  }
}

// ================= FALLBACK (ws too small; raw-W staging path) ==============
__global__ __launch_bounds__(256) void emb_small(
    const int* __restrict__ value, const int* __restrict__ depth,
    const int* __restrict__ position,
    const float* __restrict__ ve0, const float* __restrict__ pe0, const float* __restrict__ de0,
    const float* __restrict__ ve1, const float* __restrict__ pe1, const float* __restrict__ de1,
    const float* __restrict__ ve2, const float* __restrict__ pe2, const float* __restrict__ de2,
    float* __restrict__ out) {
  const int tok = blockIdx.x * 4 + (threadIdx.x >> 6);
  const int lane = threadIdx.x & 63;
  const int b = tok / 584;
  const int t = tok - b * 584;
  const float *ve, *pe, *de;
  if (t < 8)       { ve = ve0; pe = pe0; de = de0; }
  else if (t < 72) { ve = ve1; pe = pe1; de = de1; }
  else             { ve = ve2; pe = pe2; de = de2; }
  const long base = (long)b * S_TOT + t;
  const int v = value[base];
  const int d = depth[base];
  const int p0 = position[base * 3 + 0];
  const int p1 = position[base * 3 + 1];
  const int p2 = position[base * 3 + 2];
  const int e = lane * 4;
  const float4 x = *(const float4*)(ve + v * EMB + e);
  const float4 y = *(const float4*)(pe + p0 * EMB + e);
  const float4 z = *(const float4*)(pe + (64 + p1) * EMB + e);
  const float4 u = *(const float4*)(pe + (128 + p2) * EMB + e);
  const float4 w = *(const float4*)(de + d * EMB + e);
  float4 r;
  r.x = x.x + y.x + z.x + u.x + w.x;
  r.y = x.y + y.y + z.y + u.y + w.y;
  r.z = x.z + y.z + z.z + u.z + w.z;
  r.w = x.w + y.w + z.w + u.w + w.w;
  *(float4*)(out + ((long)b * OUT_T + t) * EMB + e) = r;
}

template <int K, int LOG2T, int CK, int S0, int OUT0>
__device__ __forceinline__ void conv_tile(
    int bid, const int* __restrict__ value, const int* __restrict__ position,
    const float* __restrict__ ve, const float* __restrict__ pe,
    const float* __restrict__ wraw, const float* __restrict__ bias,
    float* __restrict__ out,
    u16 (*As)[64 * 32], u16 (*Bs)[256 * 32], unsigned* idxc) {
  constexpr int T = 1 << LOG2T;
  constexpr int NS = K / 32;
  const int tid = threadIdx.x;
  const int lane = tid & 63;
  const int wid = tid >> 6;
  const int wr = wid >> 2;
  const int wc = wid & 3;
  const int fr = lane & 15;
  const int fq = lane >> 4;
  const int row0 = bid * 64;
  for (int e = tid; e < 64 * CK; e += 512) {
    const int r = e / CK, kk = e % CK;
    const int grow = row0 + r;
    const int b = grow >> LOG2T;
    const int to = grow & (T - 1);
    const long sidx = (long)b * S_TOT + (S0 + to * CK + kk);
    const int* pp = position + sidx * 3;
    idxc[e] = (unsigned)value[sidx] | ((unsigned)pp[0] << 8) |
              ((unsigned)pp[1] << 16) | ((unsigned)pp[2] << 24);
  }
  __syncthreads();
  const int arow = tid >> 3;
  const int acg = tid & 7;
  const int agran = acg >> 1, ahalf = acg & 1;
  const int aoff = arow * 32 + (agran ^ ((arow >> 1) & 3)) * 8 + ahalf * 4;
  auto gatherA = [&](int s, float4& r) {
    const int kk = s >> 3;
    const int e0 = (s & 7) * 32 + acg * 4;
    const unsigned q = idxc[arow * CK + kk];
    const int v = q & 255, p0 = (q >> 8) & 255, p1 = (q >> 16) & 255, p2 = q >> 24;
    float4 x = *(const float4*)(ve + v * EMB + e0);
    float4 y = *(const float4*)(pe + p0 * EMB + e0);
    float4 z = *(const float4*)(pe + (64 + p1) * EMB + e0);
    float4 u = *(const float4*)(pe + (128 + p2) * EMB + e0);
    r.x = x.x + y.x + z.x + u.x;
    r.y = x.y + y.y + z.y + u.y;
    r.z = x.z + y.z + z.z + u.z;
    r.w = x.w + y.w + z.w + u.w;
  };
  auto writeA = [&](int buf, const float4& r) {
    u16x4 p;
    p[0] = f2bf(r.x); p[1] = f2bf(r.y); p[2] = f2bf(r.z); p[3] = f2bf(r.w);
    *(u16x4*)(&As[buf][aoff]) = p;
  };
  auto issueB = [&](int s, int buf) {
    const int o = tid >> 1;
    const int hr = tid & 1;
    const int kk = s >> 3, e0 = (s & 7) * 32;
    const int osw = (o >> 1) & 3;
#pragma unroll
    for (int g2 = 0; g2 < 2; ++g2) {
      const int g = hr * 2 + g2;
      u16x8 r;
#pragma unroll
      for (int c = 0; c < 8; ++c)
        r[c] = f2bf(wraw[(long)o * (EMB * CK) + (e0 + g * 8 + c) * CK + kk]);
      *(u16x8*)(&Bs[buf][o * 32 + (g ^ osw) * 8]) = r;
    }
  };
  f32x4 acc[2][4];
#pragma unroll
  for (int m = 0; m < 2; ++m)
#pragma unroll
    for (int n = 0; n < 4; ++n) acc[m][n] = (f32x4){0.f, 0.f, 0.f, 0.f};
  {
    float4 a0;
    gatherA(0, a0);
    issueB(0, 0);
    writeA(0, a0);
  }
  __syncthreads();
  int cur = 0;
  for (int s = 0; s < NS; ++s) {
    const int nxt = cur ^ 1;
    const bool more = (s + 1 < NS);
    float4 pa;
    if (more) {
      gatherA(s + 1, pa);
      issueB(s + 1, nxt);
    }
    bf16x8 af[2], bfv[4];
#pragma unroll
    for (int m = 0; m < 2; ++m) {
      const int r = wr * 32 + m * 16 + fr;
      u16x8 t = *(const u16x8*)(&As[cur][r * 32 + (fq ^ ((r >> 1) & 3)) * 8]);
      af[m] = __builtin_bit_cast(bf16x8, t);
    }
#pragma unroll
    for (int n = 0; n < 4; ++n) {
      const int o = wc * 64 + n * 16 + fr;
      u16x8 t = *(const u16x8*)(&Bs[cur][o * 32 + (fq ^ ((o >> 1) & 3)) * 8]);
      bfv[n] = __builtin_bit_cast(bf16x8, t);
    }
#pragma unroll
    for (int m = 0; m < 2; ++m)
#pragma unroll
      for (int n = 0; n < 4; ++n)
        acc[m][n] = __builtin_amdgcn_mfma_f32_16x16x32_bf16(af[m], bfv[n], acc[m][n], 0, 0, 0);
    if (more) writeA(nxt, pa);
    __syncthreads();
    cur = nxt;
  }
  float bz[4];
#pragma unroll
  for (int n = 0; n < 4; ++n) bz[n] = bias[wc * 64 + n * 16 + fr];
#pragma unroll
  for (int m = 0; m < 2; ++m) {
#pragma unroll
    for (int reg = 0; reg < 4; ++reg) {
      const int grow = row0 + wr * 32 + m * 16 + fq * 4 + reg;
      const int bb = grow >> LOG2T;
      const int to = grow & (T - 1);
      float* op = out + ((long)bb * OUT_T + OUT0 + to) * EMB + wc * 64 + fr;
#pragma unroll
      for (int n = 0; n < 4; ++n) op[n * 16] = acc[m][n][reg] + bz[n];
    }
  }
}

__global__ __launch_bounds__(512, 4) void conv_fused(
    const int* __restrict__ value, const int* __restrict__ position,
    const float* __restrict__ ve3, const float* __restrict__ pe3,
    const float* __restrict__ w3, const float* __restrict__ b3,
    const float* __restrict__ ve4, const float* __restrict__ pe4,
    const float* __restrict__ w4, const float* __restrict__ b4,
    float* __restrict__ out) {
  __shared__ __align__(16) u16 As[2][64 * 32];
  __shared__ __align__(16) u16 Bs[2][256 * 32];
  __shared__ __align__(16) unsigned idxc[64 * 8];
  const int g = blockIdx.x / 5, r = blockIdx.x % 5;
  if (r == 0)
    conv_tile<1024, 10, 4, 584, 584>(g, value, position, ve3, pe3, w3, b3,
                                     out, As, Bs, idxc);
  else
    conv_tile<2048, 12, 8, 4680, 1608>(g * 4 + (r - 1), value, position, ve4,
                                       pe4, w4, b4, out, As, Bs, idxc);
}

extern "C" void kernel_launch(void* const* d_in, const int* in_sizes, int n_in,
                              void* d_out, int out_size, void* d_ws, size_t ws_size,
                              hipStream_t stream) {
  const int* value = (const int*)d_in[0];
  const int* depth = (const int*)d_in[1];
  const int* position = (const int*)d_in[2];
  const float* ve0 = (const float*)d_in[3];
  const float* pe0 = (const float*)d_in[4];
  const float* ve1 = (const float*)d_in[5];
  const float* pe1 = (const float*)d_in[6];
  const float* ve2 = (const float*)d_in[7];
  const float* pe2 = (const float*)d_in[8];
  const float* ve3 = (const float*)d_in[9];
  const float* pe3 = (const float*)d_in[10];
  const float* ve4 = (const float*)d_in[11];
  const float* pe4 = (const float*)d_in[12];
  const float* de0 = (const float*)d_in[13];
  const float* de1 = (const float*)d_in[14];
  const float* de2 = (const float*)d_in[15];
  const float* w3 = (const float*)d_in[16];
  const float* b3 = (const float*)d_in[17];
  const float* w4 = (const float*)d_in[18];
  const float* b4 = (const float*)d_in[19];
  float* out = (float*)d_out;

  u16* wt3 = (u16*)d_ws;
  u16* wt4 = wt3 + 256 * 1024;
  u16* Tm = wt4 + 256 * 2048;
  const size_t need = (size_t)(256 * 1024 + 256 * 2048 + 12 * TSZ) * sizeof(u16);

  if (ws_size >= need) {
    transpose_w<<<(256 * 2048) / 256, 256, 0, stream>>>(w3, w4, wt3, wt4);
    proj_tables<<<144, 256, 0, stream>>>(ve3, pe3, wt3, ve4, pe4, wt4, Tm);
    fused_main<<<2852, 256, 0, stream>>>(value, depth, position,
                                         Tm, b3, Tm + 4 * TSZ, b4,
                                         ve0, pe0, de0, ve1, pe1, de1,
                                         ve2, pe2, de2, out);
  } else {
    emb_small<<<1168, 256, 0, stream>>>(value, depth, position, ve0, pe0, de0,
                                        ve1, pe1, de1, ve2, pe2, de2, out);
    conv_fused<<<640, 512, 0, stream>>>(value, position, ve3, pe3, w3, b3,
                                        ve4, pe4, w4, b4, out);
  }
}